// Round 5
// baseline (1716.797 us; speedup 1.0000x reference)
//
#include <hip/hip_runtime.h>
#include <math.h>

#define L      1024
#define DM     512
#define DIN    1024
#define NH     16
#define HD     64
#define DST    64
#define CDIM   1152
#define DPROJ  2192
#define NC     16
#define CQ     64
#define EPSV   1e-5f
#define SQRTD  22.62741699796952f

__device__ __forceinline__ float siluf(float x){ return x/(1.f+__expf(-x)); }
__device__ __forceinline__ float softplusf(float x){ return (x>20.f)? x : log1pf(__expf(x)); }

#define TILE_FMA(acc, av, bv) do { \
  acc[0][0]=fmaf(av.x,bv.x,acc[0][0]); acc[0][1]=fmaf(av.x,bv.y,acc[0][1]); \
  acc[0][2]=fmaf(av.x,bv.z,acc[0][2]); acc[0][3]=fmaf(av.x,bv.w,acc[0][3]); \
  acc[1][0]=fmaf(av.y,bv.x,acc[1][0]); acc[1][1]=fmaf(av.y,bv.y,acc[1][1]); \
  acc[1][2]=fmaf(av.y,bv.z,acc[1][2]); acc[1][3]=fmaf(av.y,bv.w,acc[1][3]); \
  acc[2][0]=fmaf(av.z,bv.x,acc[2][0]); acc[2][1]=fmaf(av.z,bv.y,acc[2][1]); \
  acc[2][2]=fmaf(av.z,bv.z,acc[2][2]); acc[2][3]=fmaf(av.z,bv.w,acc[2][3]); \
  acc[3][0]=fmaf(av.w,bv.x,acc[3][0]); acc[3][1]=fmaf(av.w,bv.y,acc[3][1]); \
  acc[3][2]=fmaf(av.w,bv.z,acc[3][2]); acc[3][3]=fmaf(av.w,bv.w,acc[3][3]); \
} while(0)

// ---------------- embedding (+ reversed copy for bwd chain) ----------------
__global__ __launch_bounds__(128) void k_embed(const int* __restrict__ tok,
    const float* __restrict__ W, float* __restrict__ X){
  int t = blockIdx.x, tid = threadIdx.x;
  int token = tok[t];
  float4 v = *(const float4*)(W + (size_t)token*DM + tid*4);
  v.x*=SQRTD; v.y*=SQRTD; v.z*=SQRTD; v.w*=SQRTD;
  *(float4*)(X + (size_t)t*DM + tid*4) = v;
  *(float4*)(X + (size_t)L*DM + (size_t)(L-1-t)*DM + tid*4) = v;
}

// ---------------- layernorm over 512, per-dir weights ----------------------
__global__ __launch_bounds__(128) void k_ln(const float* __restrict__ src, float* __restrict__ dst,
    const float* __restrict__ w0, const float* __restrict__ b0,
    const float* __restrict__ w1, const float* __restrict__ b1, int rows_per_dir){
  int r = blockIdx.x, tid = threadIdx.x;
  const float* w  = (r<rows_per_dir)? w0 : w1;
  const float* bb = (r<rows_per_dir)? b0 : b1;
  float4 v = *(const float4*)(src + (size_t)r*DM + tid*4);
  float s = v.x+v.y+v.z+v.w;
  float q = v.x*v.x+v.y*v.y+v.z*v.z+v.w*v.w;
  #pragma unroll
  for (int o=1;o<64;o<<=1){ s += __shfl_xor(s,o); q += __shfl_xor(q,o); }
  __shared__ float sh[4];
  if ((tid&63)==0){ sh[(tid>>6)*2]=s; sh[(tid>>6)*2+1]=q; }
  __syncthreads();
  s = sh[0]+sh[2]; q = sh[1]+sh[3];
  float m = s*(1.f/DM);
  float rs = rsqrtf(q*(1.f/DM) - m*m + EPSV);
  float4 wv = *(const float4*)(w + tid*4);
  float4 bv = *(const float4*)(bb + tid*4);
  float4 o4;
  o4.x=(v.x-m)*rs*wv.x+bv.x; o4.y=(v.y-m)*rs*wv.y+bv.y;
  o4.z=(v.z-m)*rs*wv.z+bv.z; o4.w=(v.w-m)*rs*wv.w+bv.w;
  *(float4*)(dst + (size_t)r*DM + tid*4) = o4;
}

// ---------------- fp32 NT GEMM: C[M,N] (+=) A[M,K] * B[N,K]^T ---------------
// B pointer selected per m-tile (fwd rows < msplit, bwd rows >= msplit).
template<int RES>
__global__ __launch_bounds__(256) void k_gemm(const float* __restrict__ A,
    const float* __restrict__ B0, const float* __restrict__ B1, int msplit,
    float* __restrict__ C, int M, int N, int K){
  __shared__ __align__(16) float As[16][68];
  __shared__ __align__(16) float Bs[16][68];
  int n0 = blockIdx.x*64, m0 = blockIdx.y*64;
  const float* Bp = (m0 >= msplit) ? B1 : B0;
  int tid = threadIdx.x;
  int lm = tid>>2, lk = (tid&3)<<2;
  int tx = tid&15, ty = tid>>4;
  float acc[4][4] = {};
  const float* Ap = A + (size_t)(m0+lm)*K + lk;
  bool bval = (n0+lm) < N;
  const float* Bq = Bp + (size_t)(n0+lm)*K + lk;
  for (int k0=0;k0<K;k0+=16){
    float4 a = *(const float4*)(Ap + k0);
    float4 b = bval ? *(const float4*)(Bq + k0) : make_float4(0.f,0.f,0.f,0.f);
    As[lk+0][lm]=a.x; As[lk+1][lm]=a.y; As[lk+2][lm]=a.z; As[lk+3][lm]=a.w;
    Bs[lk+0][lm]=b.x; Bs[lk+1][lm]=b.y; Bs[lk+2][lm]=b.z; Bs[lk+3][lm]=b.w;
    __syncthreads();
    #pragma unroll
    for (int k=0;k<16;k++){
      float4 av = *(const float4*)(&As[k][ty*4]);
      float4 bv = *(const float4*)(&Bs[k][tx*4]);
      TILE_FMA(acc, av, bv);
    }
    __syncthreads();
  }
  if (n0 + tx*4 < N){
    #pragma unroll
    for (int i2=0;i2<4;i2++){
      float* cp = C + (size_t)(m0+ty*4+i2)*N + n0 + tx*4;
      float4 o4;
      if (RES){
        float4 c4 = *(const float4*)cp;
        o4.x=c4.x+acc[i2][0]; o4.y=c4.y+acc[i2][1];
        o4.z=c4.z+acc[i2][2]; o4.w=c4.w+acc[i2][3];
      } else {
        o4.x=acc[i2][0]; o4.y=acc[i2][1]; o4.z=acc[i2][2]; o4.w=acc[i2][3];
      }
      *(float4*)cp = o4;
    }
  }
}

// ---------------- causal depthwise conv(4) + bias + silu -------------------
__global__ __launch_bounds__(256) void k_conv(const float* __restrict__ ZX,
    const float* __restrict__ cw0, const float* __restrict__ cb0,
    const float* __restrict__ cw1, const float* __restrict__ cb1,
    float* __restrict__ XC){
  int r = blockIdx.x;            // d*L + t
  int d = r >> 10, t = r & (L-1);
  const float* cw = d ? cw1 : cw0;
  const float* cb = d ? cb1 : cb0;
  const float* base = ZX + (size_t)r*DPROJ + DIN;
  float* out = XC + (size_t)r*CDIM;
  for (int j = threadIdx.x; j < CDIM/4; j += 256){
    int c = j*4;
    float4 w0 = *(const float4*)(cw + (size_t)(c+0)*4);
    float4 w1 = *(const float4*)(cw + (size_t)(c+1)*4);
    float4 w2 = *(const float4*)(cw + (size_t)(c+2)*4);
    float4 w3 = *(const float4*)(cw + (size_t)(c+3)*4);
    float4 acc = *(const float4*)(cb + c);
    #pragma unroll
    for (int k=0;k<4;k++){
      int tt = t - 3 + k;
      if (tt >= 0){
        float4 xv = *(const float4*)(base + (ptrdiff_t)(k-3)*DPROJ + c);
        acc.x = fmaf(xv.x, (&w0.x)[k], acc.x);
        acc.y = fmaf(xv.y, (&w1.x)[k], acc.y);
        acc.z = fmaf(xv.z, (&w2.x)[k], acc.z);
        acc.w = fmaf(xv.w, (&w3.x)[k], acc.w);
      }
    }
    acc.x=siluf(acc.x); acc.y=siluf(acc.y); acc.z=siluf(acc.z); acc.w=siluf(acc.w);
    *(float4*)(out + c) = acc;
  }
}

// ------------- dt=softplus(raw+bias); per-chunk cumsum of log(dA) ----------
__global__ __launch_bounds__(256) void k_dtcum(const float* __restrict__ ZX,
    const float* __restrict__ db0, const float* __restrict__ al0,
    const float* __restrict__ db1, const float* __restrict__ al1,
    float* __restrict__ DT, float* __restrict__ LAb){
  int idx = blockIdx.x*256 + threadIdx.x;
  if (idx >= 2*NH*NC) return;
  int d = idx >> 8, rem = idx & 255, h = rem >> 4, c = rem & 15;
  float bias = (d? db1: db0)[h];
  float eA   = __expf((d? al1: al0)[h]);
  float sum = 0.f;
  const float* zp = ZX + (size_t)d*L*DPROJ + (size_t)c*CQ*DPROJ + (DIN+CDIM) + h;
  float* dtp = DT + (size_t)d*L*NH + (size_t)c*CQ*NH + h;
  float* lap = LAb + (((size_t)d*NH + h)*NC + c)*CQ;
  for (int i=0;i<CQ;i++){
    float dtv = softplusf(zp[(size_t)i*DPROJ] + bias);
    dtp[(size_t)i*NH] = dtv;
    sum += -dtv*eA;
    lap[i] = sum;
  }
}

// ------------- scan step A: intra-chunk Y + chunk-state contribution -------
__global__ __launch_bounds__(256) void k_scanA(const float* __restrict__ XC,
    const float* __restrict__ DT, const float* __restrict__ LAb,
    float* __restrict__ Y, float* __restrict__ ZB){
  __shared__ __align__(16) float BT[64][64];   // phase1: B^T[n][j]; phase3: B row-major [j][n]
  __shared__ __align__(16) float CT[64][68];   // phase1: C^T[n][i]; phase2+: M^T[j][i]
  __shared__ __align__(16) float Xsh[64][68];  // X[j][p]
  __shared__ float lash[64], dtsh[64], wsh[64];
  int c = blockIdx.x, h = blockIdx.y, d = blockIdx.z;
  int tid = threadIdx.x;
  const float* xcb = XC + (size_t)d*L*CDIM + (size_t)c*CQ*CDIM;
  for (int idx=tid; idx<64*16; idx+=256){
    int row = idx>>4, q = idx&15, n = q*4;
    const float* rp = xcb + (size_t)row*CDIM;
    float4 xb = *(const float4*)(rp + DIN + n);
    float4 xc = *(const float4*)(rp + DIN + DST + n);
    float4 xx = *(const float4*)(rp + h*HD + n);
    BT[n][row]=xb.x; BT[n+1][row]=xb.y; BT[n+2][row]=xb.z; BT[n+3][row]=xb.w;
    CT[n][row]=xc.x; CT[n+1][row]=xc.y; CT[n+2][row]=xc.z; CT[n+3][row]=xc.w;
    Xsh[row][n]=xx.x; Xsh[row][n+1]=xx.y; Xsh[row][n+2]=xx.z; Xsh[row][n+3]=xx.w;
  }
  if (tid < 64){
    lash[tid] = LAb[(((size_t)d*NH+h)*NC+c)*CQ + tid];
    dtsh[tid] = DT[(size_t)d*L*NH + (size_t)(c*CQ+tid)*NH + h];
  }
  __syncthreads();
  if (tid < 64) wsh[tid] = __expf(lash[63]-lash[tid])*dtsh[tid];
  int tx = tid&15, ty = tid>>4;
  // G[i][j] = C_i . B_j
  float g[4][4] = {};
  for (int n=0;n<64;n++){
    float4 cv = *(const float4*)(&CT[n][ty*4]);
    float4 bv = *(const float4*)(&BT[n][tx*4]);
    TILE_FMA(g, cv, bv);
  }
  // M[i][j] = (j<=i) ? G * exp(la_i - la_j) * dt_j : 0
  float mm[4][4];
  #pragma unroll
  for (int a=0;a<4;a++){
    int i = ty*4+a; float li = lash[i];
    #pragma unroll
    for (int b2=0;b2<4;b2++){
      int j = tx*4+b2;
      mm[a][b2] = (j<=i) ? g[a][b2]*__expf(li-lash[j])*dtsh[j] : 0.f;
    }
  }
  __syncthreads();           // all BT/CT reads done
  #pragma unroll
  for (int a=0;a<4;a++)
    #pragma unroll
    for (int b2=0;b2<4;b2++)
      CT[tx*4+b2][ty*4+a] = mm[a][b2];       // M^T[j][i]
  // reload B row-major into BT region (needed by Z phase)
  for (int idx=tid; idx<64*16; idx+=256){
    int row = idx>>4, q = idx&15, n = q*4;
    float4 xb = *(const float4*)(xcb + (size_t)row*CDIM + DIN + n);
    BT[row][n]=xb.x; BT[row][n+1]=xb.y; BT[row][n+2]=xb.z; BT[row][n+3]=xb.w;
  }
  __syncthreads();
  // Y_intra[i][p] = sum_j M[i][j] X[j][p]
  float yv[4][4] = {};
  for (int j=0;j<64;j++){
    float4 mv = *(const float4*)(&CT[j][ty*4]);
    float4 xv = *(const float4*)(&Xsh[j][tx*4]);
    TILE_FMA(yv, mv, xv);
  }
  float* yb = Y + (size_t)d*L*DIN + (size_t)c*CQ*DIN + (size_t)h*HD;
  #pragma unroll
  for (int a=0;a<4;a++){
    float4 o4 = make_float4(yv[a][0],yv[a][1],yv[a][2],yv[a][3]);
    *(float4*)(yb + (size_t)(ty*4+a)*DIN + tx*4) = o4;
  }
  // Z[p][n] = sum_j w_j X[j][p] B_j[n]
  float zz[4][4] = {};
  for (int j=0;j<64;j++){
    float w = wsh[j];
    float4 xv = *(const float4*)(&Xsh[j][ty*4]);
    float4 bv = *(const float4*)(&BT[j][tx*4]);
    float4 xw = make_float4(xv.x*w, xv.y*w, xv.z*w, xv.w*w);
    TILE_FMA(zz, xw, bv);
  }
  float* zb = ZB + (((size_t)d*NH+h)*NC + (size_t)c)*HD*DST;
  #pragma unroll
  for (int a=0;a<4;a++){
    float4 o4 = make_float4(zz[a][0],zz[a][1],zz[a][2],zz[a][3]);
    *(float4*)(zb + (size_t)(ty*4+a)*DST + tx*4) = o4;
  }
}

// ------------- scan step B: sequential chunk-state carry (16 steps) --------
#define UPD4(s,zv_) s.x=fmaf(s.x,ct,zv_.x); s.y=fmaf(s.y,ct,zv_.y); s.z=fmaf(s.z,ct,zv_.z); s.w=fmaf(s.w,ct,zv_.w);
__global__ __launch_bounds__(256) void k_scanB(const float* __restrict__ ZB,
    const float* __restrict__ LAb, float* __restrict__ SB){
  int h = blockIdx.x, d = blockIdx.y;
  int tid = threadIdx.x;
  int p = tid>>2, n0 = (tid&3)<<4;
  size_t hb = ((size_t)d*NH+h)*NC*HD*DST;
  size_t po = (size_t)p*DST + n0;
  const float* lap = LAb + ((size_t)d*NH+h)*NC*CQ;
  float4 s0=make_float4(0,0,0,0), s1=s0, s2=s0, s3=s0;
  for (int c=0;c<NC;c++){
    size_t off = hb + (size_t)c*HD*DST + po;
    *(float4*)(SB+off+0)  = s0;
    *(float4*)(SB+off+4)  = s1;
    *(float4*)(SB+off+8)  = s2;
    *(float4*)(SB+off+12) = s3;
    float ct = __expf(lap[c*CQ+63]);
    float4 z0 = *(const float4*)(ZB+off+0);
    float4 z1 = *(const float4*)(ZB+off+4);
    float4 z2 = *(const float4*)(ZB+off+8);
    float4 z3 = *(const float4*)(ZB+off+12);
    UPD4(s0,z0); UPD4(s1,z1); UPD4(s2,z2); UPD4(s3,z3);
  }
}

// ------------- scan step C: inter-chunk Y + D skip, into Y -----------------
__global__ __launch_bounds__(256) void k_scanC(const float* __restrict__ XC,
    const float* __restrict__ SB, const float* __restrict__ LAb,
    const float* __restrict__ D0, const float* __restrict__ D1,
    float* __restrict__ Y){
  __shared__ __align__(16) float CT[64][64];   // C^T[n][i]
  __shared__ __align__(16) float ST[64][68];   // S^T[n][p]
  __shared__ float lash[64];
  int c = blockIdx.x, h = blockIdx.y, d = blockIdx.z;
  int tid = threadIdx.x;
  const float* xcb = XC + (size_t)d*L*CDIM + (size_t)c*CQ*CDIM;
  const float* sb = SB + (((size_t)d*NH+h)*NC + (size_t)c)*HD*DST;
  for (int idx=tid; idx<64*16; idx+=256){
    int row = idx>>4, q = idx&15, n = q*4;
    float4 xc = *(const float4*)(xcb + (size_t)row*CDIM + DIN + DST + n);
    float4 sv = *(const float4*)(sb + (size_t)row*DST + n);
    CT[n][row]=xc.x; CT[n+1][row]=xc.y; CT[n+2][row]=xc.z; CT[n+3][row]=xc.w;
    ST[n][row]=sv.x; ST[n+1][row]=sv.y; ST[n+2][row]=sv.z; ST[n+3][row]=sv.w;
  }
  if (tid<64) lash[tid] = LAb[(((size_t)d*NH+h)*NC+c)*CQ + tid];
  __syncthreads();
  int tx=tid&15, ty=tid>>4;
  float acc[4][4] = {};
  for (int n=0;n<64;n++){
    float4 cv = *(const float4*)(&CT[n][ty*4]);
    float4 sv = *(const float4*)(&ST[n][tx*4]);
    TILE_FMA(acc, cv, sv);
  }
  float Dh = (d? D1 : D0)[h];
  float* yb = Y + (size_t)d*L*DIN + (size_t)c*CQ*DIN + (size_t)h*HD;
  #pragma unroll
  for (int a=0;a<4;a++){
    int i = ty*4+a;
    float el = __expf(lash[i]);
    float4 xv = *(const float4*)(xcb + (size_t)i*CDIM + h*HD + tx*4);
    float* yp = yb + (size_t)i*DIN + tx*4;
    float4 y4 = *(const float4*)yp;
    y4.x += el*acc[a][0] + Dh*xv.x;
    y4.y += el*acc[a][1] + Dh*xv.y;
    y4.z += el*acc[a][2] + Dh*xv.z;
    y4.w += el*acc[a][3] + Dh*xv.w;
    *(float4*)yp = y4;
  }
}

// ------------- gated RMSNorm: XG = rms(y*silu(z)) * norm_w -----------------
__global__ __launch_bounds__(256) void k_rms(const float* __restrict__ Y,
    const float* __restrict__ ZX, const float* __restrict__ nw0,
    const float* __restrict__ nw1, float* __restrict__ XG){
  int r = blockIdx.x;
  int d = r >> 10;
  const float* nw = d? nw1 : nw0;
  int tid = threadIdx.x;
  float4 yv = *(const float4*)(Y + (size_t)r*DIN + tid*4);
  float4 zv = *(const float4*)(ZX + (size_t)r*DPROJ + tid*4);
  float4 gv;
  gv.x=yv.x*siluf(zv.x); gv.y=yv.y*siluf(zv.y);
  gv.z=yv.z*siluf(zv.z); gv.w=yv.w*siluf(zv.w);
  float q = gv.x*gv.x+gv.y*gv.y+gv.z*gv.z+gv.w*gv.w;
  #pragma unroll
  for (int o=1;o<64;o<<=1) q += __shfl_xor(q,o);
  __shared__ float sh[4];
  if ((tid&63)==0) sh[tid>>6] = q;
  __syncthreads();
  q = sh[0]+sh[1]+sh[2]+sh[3];
  float rs = rsqrtf(q*(1.f/DIN) + EPSV);
  float4 wv = *(const float4*)(nw + tid*4);
  float4 o4;
  o4.x=gv.x*rs*wv.x; o4.y=gv.y*rs*wv.y; o4.z=gv.z*rs*wv.z; o4.w=gv.w*rs*wv.w;
  *(float4*)(XG + (size_t)r*DIN + tid*4) = o4;
}

// ------------- merged = [fwd[t], bwd[L-1-t]] -------------------------------
__global__ __launch_bounds__(128) void k_merge(const float* __restrict__ X, float* __restrict__ MG){
  int t = blockIdx.x, tid = threadIdx.x;
  float4 f = *(const float4*)(X + (size_t)t*DM + tid*4);
  float4 b = *(const float4*)(X + (size_t)L*DM + (size_t)(L-1-t)*DM + tid*4);
  *(float4*)(MG + (size_t)t*2*DM + tid*4) = f;
  *(float4*)(MG + (size_t)t*2*DM + DM + tid*4) = b;
}

extern "C" void kernel_launch(void* const* d_in, const int* in_sizes, int n_in,
                              void* d_out, int out_size, void* d_ws, size_t ws_size,
                              hipStream_t stream) {
  (void)in_sizes; (void)n_in; (void)out_size; (void)ws_size;
  const int*   tokens  = (const int*)d_in[0];
  const float* embedW  = (const float*)d_in[1];
  const float* f_in_proj = (const float*)d_in[2];
  const float* f_conv_w  = (const float*)d_in[3];
  const float* f_conv_b  = (const float*)d_in[4];
  const float* f_dt_bias = (const float*)d_in[5];
  const float* f_A_log   = (const float*)d_in[6];
  const float* f_D       = (const float*)d_in[7];
  const float* f_norm_w  = (const float*)d_in[8];
  const float* f_out_proj= (const float*)d_in[9];
  const float* f_ln_w    = (const float*)d_in[10];
  const float* f_ln_b    = (const float*)d_in[11];
  const float* b_in_proj = (const float*)d_in[12];
  const float* b_conv_w  = (const float*)d_in[13];
  const float* b_conv_b  = (const float*)d_in[14];
  const float* b_dt_bias = (const float*)d_in[15];
  const float* b_A_log   = (const float*)d_in[16];
  const float* b_D       = (const float*)d_in[17];
  const float* b_norm_w  = (const float*)d_in[18];
  const float* b_out_proj= (const float*)d_in[19];
  const float* b_ln_w    = (const float*)d_in[20];
  const float* b_ln_b    = (const float*)d_in[21];
  const float* mergeW    = (const float*)d_in[22];
  const float* fin_w     = (const float*)d_in[23];
  const float* fin_b     = (const float*)d_in[24];

  float* W = (float*)d_ws;                 // ~76 MiB total workspace
  float* X  = W;  W += 2*L*DM;             // residual stream (both dirs)
  float* XN = W;  W += 2*L*DM;             // ln output / merge-gemm output
  float* ZX = W;  W += (size_t)2*L*DPROJ;  // in_proj output
  float* XC = W;  W += (size_t)2*L*CDIM;   // conv output
  float* DTb= W;  W += 2*L*NH;
  float* LAb= W;  W += 2*NH*NC*CQ;
  float* Yb = W;  W += (size_t)2*L*DIN;
  float* ZB = W;  W += (size_t)2*NH*NC*HD*DST;
  float* SB = W;  W += (size_t)2*NH*NC*HD*DST;
  float* XG = W;  W += (size_t)2*L*DIN;
  float* MG = W;  W += (size_t)L*2*DM;
  float* FN = W;  W += (size_t)L*DM;

  k_embed<<<L,128,0,stream>>>(tokens, embedW, X);
  for (int i=0;i<4;i++){
    k_ln<<<2*L,128,0,stream>>>(X, XN, f_ln_w+i*DM, f_ln_b+i*DM, b_ln_w+i*DM, b_ln_b+i*DM, L);
    k_gemm<0><<<dim3((DPROJ+63)/64, (2*L)/64),256,0,stream>>>(
        XN, f_in_proj+(size_t)i*DPROJ*DM, b_in_proj+(size_t)i*DPROJ*DM, L,
        ZX, 2*L, DPROJ, DM);
    k_conv<<<2*L,256,0,stream>>>(ZX, f_conv_w+(size_t)i*CDIM*4, f_conv_b+(size_t)i*CDIM,
                                 b_conv_w+(size_t)i*CDIM*4, b_conv_b+(size_t)i*CDIM, XC);
    k_dtcum<<<2,256,0,stream>>>(ZX, f_dt_bias+i*NH, f_A_log+i*NH,
                                b_dt_bias+i*NH, b_A_log+i*NH, DTb, LAb);
    k_scanA<<<dim3(NC,NH,2),256,0,stream>>>(XC, DTb, LAb, Yb, ZB);
    k_scanB<<<dim3(NH,2),256,0,stream>>>(ZB, LAb, SB);
    k_scanC<<<dim3(NC,NH,2),256,0,stream>>>(XC, SB, LAb, f_D+i*NH, b_D+i*NH, Yb);
    k_rms<<<2*L,256,0,stream>>>(Yb, ZX, f_norm_w+i*DIN, b_norm_w+i*DIN, XG);
    k_gemm<1><<<dim3(DM/64, (2*L)/64),256,0,stream>>>(
        XG, f_out_proj+(size_t)i*DM*DIN, b_out_proj+(size_t)i*DM*DIN, L,
        X, 2*L, DM, DIN);
  }
  k_merge<<<L,128,0,stream>>>(X, MG);
  k_gemm<0><<<dim3(DM/64, L/64),256,0,stream>>>(MG, mergeW, mergeW, 1<<30, XN, L, DM, 2*DM);
  k_ln<<<L,128,0,stream>>>(XN, FN, fin_w, fin_b, fin_w, fin_b, L);
  k_gemm<0><<<dim3(32000/64, L/64),256,0,stream>>>(FN, embedW, embedW, 1<<30,
      (float*)d_out, L, 32000, DM);
}

// Round 6
// 1074.312 us; speedup vs baseline: 1.5980x; 1.5980x over previous
//
#include <hip/hip_runtime.h>
#include <math.h>

#define L      1024
#define DM     512
#define DIN    1024
#define NH     16
#define HD     64
#define DST    64
#define CDIM   1152
#define DPROJ  2192
#define NC     16
#define CQ     64
#define EPSV   1e-5f
#define SQRTD  22.62741699796952f

#define IPS (2304*512)   // padded in_proj weights per (dir,layer)
#define OPS (512*1024)

typedef short short8v __attribute__((ext_vector_type(8)));
typedef float f32x4 __attribute__((ext_vector_type(4)));

__device__ __forceinline__ float siluf(float x){ return x/(1.f+__expf(-x)); }
__device__ __forceinline__ float softplusf(float x){ return (x>20.f)? x : log1pf(__expf(x)); }

__device__ __forceinline__ ushort bf16_rne(float f){
  union { float f; unsigned u; } v; v.f = f;
  unsigned u = v.u;
  return (ushort)((u + 0x7FFFu + ((u>>16)&1u)) >> 16);
}
__device__ __forceinline__ float bf16_f(ushort h){
  union { unsigned u; float f; } v; v.u = ((unsigned)h)<<16;
  return v.f;
}
__device__ __forceinline__ void split2(float x, ushort& hi, ushort& lo){
  ushort h = bf16_rne(x);
  hi = h;
  lo = bf16_rne(x - bf16_f(h));
}

// async global->LDS, 16B per lane (dest must be linear: base + lane*16)
#define GLOAD16(g, l) __builtin_amdgcn_global_load_lds( \
    (const __attribute__((address_space(1))) void*)(g), \
    (__attribute__((address_space(3))) void*)(l), 16, 0, 0)

#define TILE_FMA(acc, av, bv) do { \
  acc[0][0]=fmaf(av.x,bv.x,acc[0][0]); acc[0][1]=fmaf(av.x,bv.y,acc[0][1]); \
  acc[0][2]=fmaf(av.x,bv.z,acc[0][2]); acc[0][3]=fmaf(av.x,bv.w,acc[0][3]); \
  acc[1][0]=fmaf(av.y,bv.x,acc[1][0]); acc[1][1]=fmaf(av.y,bv.y,acc[1][1]); \
  acc[1][2]=fmaf(av.y,bv.z,acc[1][2]); acc[1][3]=fmaf(av.y,bv.w,acc[1][3]); \
  acc[2][0]=fmaf(av.z,bv.x,acc[2][0]); acc[2][1]=fmaf(av.z,bv.y,acc[2][1]); \
  acc[2][2]=fmaf(av.z,bv.z,acc[2][2]); acc[2][3]=fmaf(av.z,bv.w,acc[2][3]); \
  acc[3][0]=fmaf(av.w,bv.x,acc[3][0]); acc[3][1]=fmaf(av.w,bv.y,acc[3][1]); \
  acc[3][2]=fmaf(av.w,bv.z,acc[3][2]); acc[3][3]=fmaf(av.w,bv.w,acc[3][3]); \
} while(0)

// ---------------- embedding (+ reversed copy for bwd chain) ----------------
__global__ __launch_bounds__(128) void k_embed(const int* __restrict__ tok,
    const float* __restrict__ W, float* __restrict__ X){
  int t = blockIdx.x, tid = threadIdx.x;
  int token = tok[t];
  float4 v = *(const float4*)(W + (size_t)token*DM + tid*4);
  v.x*=SQRTD; v.y*=SQRTD; v.z*=SQRTD; v.w*=SQRTD;
  *(float4*)(X + (size_t)t*DM + tid*4) = v;
  *(float4*)(X + (size_t)L*DM + (size_t)(L-1-t)*DM + tid*4) = v;
}

// ---------------- layernorm over 512 -> fp32 (fallback path) ---------------
__global__ __launch_bounds__(128) void k_ln(const float* __restrict__ src, float* __restrict__ dst,
    const float* __restrict__ w0, const float* __restrict__ b0,
    const float* __restrict__ w1, const float* __restrict__ b1, int rows_per_dir){
  int r = blockIdx.x, tid = threadIdx.x;
  const float* w  = (r<rows_per_dir)? w0 : w1;
  const float* bb = (r<rows_per_dir)? b0 : b1;
  float4 v = *(const float4*)(src + (size_t)r*DM + tid*4);
  float s = v.x+v.y+v.z+v.w;
  float q = v.x*v.x+v.y*v.y+v.z*v.z+v.w*v.w;
  #pragma unroll
  for (int o=1;o<64;o<<=1){ s += __shfl_xor(s,o); q += __shfl_xor(q,o); }
  __shared__ float sh[4];
  if ((tid&63)==0){ sh[(tid>>6)*2]=s; sh[(tid>>6)*2+1]=q; }
  __syncthreads();
  s = sh[0]+sh[2]; q = sh[1]+sh[3];
  float m = s*(1.f/DM);
  float rs = rsqrtf(q*(1.f/DM) - m*m + EPSV);
  float4 wv = *(const float4*)(w + tid*4);
  float4 bv = *(const float4*)(bb + tid*4);
  float4 o4;
  o4.x=(v.x-m)*rs*wv.x+bv.x; o4.y=(v.y-m)*rs*wv.y+bv.y;
  o4.z=(v.z-m)*rs*wv.z+bv.z; o4.w=(v.w-m)*rs*wv.w+bv.w;
  *(float4*)(dst + (size_t)r*DM + tid*4) = o4;
}

// ---------------- layernorm -> split bf16 hi/lo (MFMA path) ----------------
__global__ __launch_bounds__(128) void k_ln_bf(const float* __restrict__ src,
    ushort* __restrict__ hi, ushort* __restrict__ lo,
    const float* __restrict__ w0, const float* __restrict__ b0,
    const float* __restrict__ w1, const float* __restrict__ b1, int rows_per_dir){
  int r = blockIdx.x, tid = threadIdx.x;
  const float* w  = (r<rows_per_dir)? w0 : w1;
  const float* bb = (r<rows_per_dir)? b0 : b1;
  float4 v = *(const float4*)(src + (size_t)r*DM + tid*4);
  float s = v.x+v.y+v.z+v.w;
  float q = v.x*v.x+v.y*v.y+v.z*v.z+v.w*v.w;
  #pragma unroll
  for (int o=1;o<64;o<<=1){ s += __shfl_xor(s,o); q += __shfl_xor(q,o); }
  __shared__ float sh[4];
  if ((tid&63)==0){ sh[(tid>>6)*2]=s; sh[(tid>>6)*2+1]=q; }
  __syncthreads();
  s = sh[0]+sh[2]; q = sh[1]+sh[3];
  float m = s*(1.f/DM);
  float rs = rsqrtf(q*(1.f/DM) - m*m + EPSV);
  float4 wv = *(const float4*)(w + tid*4);
  float4 bv = *(const float4*)(bb + tid*4);
  float4 o4;
  o4.x=(v.x-m)*rs*wv.x+bv.x; o4.y=(v.y-m)*rs*wv.y+bv.y;
  o4.z=(v.z-m)*rs*wv.z+bv.z; o4.w=(v.w-m)*rs*wv.w+bv.w;
  ushort4 h4, l4;
  split2(o4.x,h4.x,l4.x); split2(o4.y,h4.y,l4.y);
  split2(o4.z,h4.z,l4.z); split2(o4.w,h4.w,l4.w);
  *(ushort4*)(hi + (size_t)r*DM + tid*4) = h4;
  *(ushort4*)(lo + (size_t)r*DM + tid*4) = l4;
}

// ---------------- fp32 NT GEMM (fallback path) -----------------------------
template<int RES>
__global__ __launch_bounds__(256) void k_gemm(const float* __restrict__ A,
    const float* __restrict__ B0, const float* __restrict__ B1, int msplit,
    float* __restrict__ C, int M, int N, int K){
  __shared__ __align__(16) float As[16][68];
  __shared__ __align__(16) float Bs[16][68];
  int n0 = blockIdx.x*64, m0 = blockIdx.y*64;
  const float* Bp = (m0 >= msplit) ? B1 : B0;
  int tid = threadIdx.x;
  int lm = tid>>2, lk = (tid&3)<<2;
  int tx = tid&15, ty = tid>>4;
  float acc[4][4] = {};
  const float* Ap = A + (size_t)(m0+lm)*K + lk;
  bool bval = (n0+lm) < N;
  const float* Bq = Bp + (size_t)(n0+lm)*K + lk;
  for (int k0=0;k0<K;k0+=16){
    float4 a = *(const float4*)(Ap + k0);
    float4 b = bval ? *(const float4*)(Bq + k0) : make_float4(0.f,0.f,0.f,0.f);
    As[lk+0][lm]=a.x; As[lk+1][lm]=a.y; As[lk+2][lm]=a.z; As[lk+3][lm]=a.w;
    Bs[lk+0][lm]=b.x; Bs[lk+1][lm]=b.y; Bs[lk+2][lm]=b.z; Bs[lk+3][lm]=b.w;
    __syncthreads();
    #pragma unroll
    for (int k=0;k<16;k++){
      float4 av = *(const float4*)(&As[k][ty*4]);
      float4 bv = *(const float4*)(&Bs[k][tx*4]);
      TILE_FMA(acc, av, bv);
    }
    __syncthreads();
  }
  if (n0 + tx*4 < N){
    #pragma unroll
    for (int i2=0;i2<4;i2++){
      float* cp = C + (size_t)(m0+ty*4+i2)*N + n0 + tx*4;
      float4 o4;
      if (RES){
        float4 c4 = *(const float4*)cp;
        o4.x=c4.x+acc[i2][0]; o4.y=c4.y+acc[i2][1];
        o4.z=c4.z+acc[i2][2]; o4.w=c4.w+acc[i2][3];
      } else {
        o4.x=acc[i2][0]; o4.y=acc[i2][1]; o4.z=acc[i2][2]; o4.w=acc[i2][3];
      }
      *(float4*)cp = o4;
    }
  }
}

// ---------------- split-bf16 MFMA NT GEMM: C[M,Nt] (+=) A * B^T ------------
// A (activations) pre-split hi/lo [M][K]; B (weights) pre-split hi/lo, rows
// padded to grid (zero-filled). 3-product: AhBh + AhBl + AlBh (~fp32 acc).
// B pointer selected per m-tile (fwd m0<msplit, bwd otherwise).
template<int TM, int TN, int RES>
__global__ __launch_bounds__(256) void k_gemm_mf(
    const ushort* __restrict__ Ah, const ushort* __restrict__ Al,
    const ushort* __restrict__ Bh0, const ushort* __restrict__ Bl0,
    const ushort* __restrict__ Bh1, const ushort* __restrict__ Bl1,
    int msplit, float* __restrict__ C, int Ntrue, int K){
  constexpr int WGM = (TM==128)?2:1;
  constexpr int WGN = 4/WGM;
  constexpr int TMW = TM/WGM, TNW = TN/WGN;
  constexpr int FM = TMW/16, FN = TNW/16;
  __shared__ ushort sAh[TM*64], sAl[TM*64], sBh[TN*64], sBl[TN*64];
  int tid = threadIdx.x, lane = tid&63, wid = tid>>6;
  int wm = (wid/WGN)*TMW, wn = (wid%WGN)*TNW;
  int lrow = lane&15, kg = lane>>4;
  int m0 = blockIdx.y*TM, n0 = blockIdx.x*TN;
  const ushort* Bh = (m0>=msplit)? Bh1 : Bh0;
  const ushort* Bl = (m0>=msplit)? Bl1 : Bl0;
  f32x4 acc[FM][FN] = {};
  for (int k0=0;k0<K;k0+=64){
    #pragma unroll
    for (int i=0;i<TM/32;i++){
      int off=(i*256+tid)*8, r=off>>6, cc=off&63;
      size_t gs=(size_t)(m0+r)*K + k0 + cc;
      GLOAD16(Ah+gs, &sAh[off]);
      GLOAD16(Al+gs, &sAl[off]);
    }
    #pragma unroll
    for (int i=0;i<TN/32;i++){
      int off=(i*256+tid)*8, r=off>>6, cc=off&63;
      size_t gs=(size_t)(n0+r)*K + k0 + cc;
      GLOAD16(Bh+gs, &sBh[off]);
      GLOAD16(Bl+gs, &sBl[off]);
    }
    __syncthreads();
    #pragma unroll
    for (int kk=0;kk<2;kk++){
      short8v av_h[FM], av_l[FM], bv_h[FN], bv_l[FN];
      #pragma unroll
      for (int f=0;f<FM;f++){
        int o=(wm+f*16+lrow)*64 + kk*32 + kg*8;
        av_h[f]=*(const short8v*)&sAh[o];
        av_l[f]=*(const short8v*)&sAl[o];
      }
      #pragma unroll
      for (int f=0;f<FN;f++){
        int o=(wn+f*16+lrow)*64 + kk*32 + kg*8;
        bv_h[f]=*(const short8v*)&sBh[o];
        bv_l[f]=*(const short8v*)&sBl[o];
      }
      #pragma unroll
      for (int fm=0;fm<FM;fm++)
        #pragma unroll
        for (int fn=0;fn<FN;fn++){
          acc[fm][fn]=__builtin_amdgcn_mfma_f32_16x16x32_bf16(av_h[fm],bv_h[fn],acc[fm][fn],0,0,0);
          acc[fm][fn]=__builtin_amdgcn_mfma_f32_16x16x32_bf16(av_h[fm],bv_l[fn],acc[fm][fn],0,0,0);
          acc[fm][fn]=__builtin_amdgcn_mfma_f32_16x16x32_bf16(av_l[fm],bv_h[fn],acc[fm][fn],0,0,0);
        }
    }
    __syncthreads();
  }
  // C/D layout (m89-verified): col = lane&15, row = (lane>>4)*4 + reg
  #pragma unroll
  for (int fm=0;fm<FM;fm++)
    #pragma unroll
    for (int fn=0;fn<FN;fn++){
      int col = n0 + wn + fn*16 + lrow;
      if (col < Ntrue){
        #pragma unroll
        for (int r=0;r<4;r++){
          int row = m0 + wm + fm*16 + kg*4 + r;
          float* cp = C + (size_t)row*Ntrue + col;
          float v = acc[fm][fn][r];
          *cp = RES ? (*cp + v) : v;
        }
      }
    }
}

// ---------------- weight split kernels -------------------------------------
__global__ __launch_bounds__(256) void k_split_flat(const float* __restrict__ src,
    ushort* __restrict__ hi, ushort* __restrict__ lo, int n8){
  int i = blockIdx.x*256 + threadIdx.x;
  if (i >= n8) return;
  size_t e0 = (size_t)i*8;
  float4 v0 = *(const float4*)(src+e0);
  float4 v1 = *(const float4*)(src+e0+4);
  ushort4 h0,l0,h1,l1;
  split2(v0.x,h0.x,l0.x); split2(v0.y,h0.y,l0.y); split2(v0.z,h0.z,l0.z); split2(v0.w,h0.w,l0.w);
  split2(v1.x,h1.x,l1.x); split2(v1.y,h1.y,l1.y); split2(v1.z,h1.z,l1.z); split2(v1.w,h1.w,l1.w);
  *(ushort4*)(hi+e0)=h0; *(ushort4*)(hi+e0+4)=h1;
  *(ushort4*)(lo+e0)=l0; *(ushort4*)(lo+e0+4)=l1;
}

// in_proj: [4][2192][512] -> padded [4][2304][512], zero-filled pad rows
__global__ __launch_bounds__(256) void k_split_ip(const float* __restrict__ src,
    ushort* __restrict__ hi, ushort* __restrict__ lo){
  int i = blockIdx.x*256 + threadIdx.x;     // grid covers 4*2304*512/8 exactly
  size_t e0 = (size_t)i*8;
  int row = (int)(e0>>9), col = (int)(e0&511);
  int layer = row/2304, rr = row - layer*2304;
  ushort4 h0={0,0,0,0}, l0={0,0,0,0}, h1={0,0,0,0}, l1={0,0,0,0};
  if (rr < 2192){
    const float* sp = src + ((size_t)(layer*2192+rr)<<9) + col;
    float4 v0 = *(const float4*)(sp);
    float4 v1 = *(const float4*)(sp+4);
    split2(v0.x,h0.x,l0.x); split2(v0.y,h0.y,l0.y); split2(v0.z,h0.z,l0.z); split2(v0.w,h0.w,l0.w);
    split2(v1.x,h1.x,l1.x); split2(v1.y,h1.y,l1.y); split2(v1.z,h1.z,l1.z); split2(v1.w,h1.w,l1.w);
  }
  *(ushort4*)(hi+e0)=h0; *(ushort4*)(hi+e0+4)=h1;
  *(ushort4*)(lo+e0)=l0; *(ushort4*)(lo+e0+4)=l1;
}

// ---------------- causal depthwise conv(4) + bias + silu -------------------
__global__ __launch_bounds__(256) void k_conv(const float* __restrict__ ZX,
    const float* __restrict__ cw0, const float* __restrict__ cb0,
    const float* __restrict__ cw1, const float* __restrict__ cb1,
    float* __restrict__ XC){
  int r = blockIdx.x;            // d*L + t
  int d = r >> 10, t = r & (L-1);
  const float* cw = d ? cw1 : cw0;
  const float* cb = d ? cb1 : cb0;
  const float* base = ZX + (size_t)r*DPROJ + DIN;
  float* out = XC + (size_t)r*CDIM;
  for (int j = threadIdx.x; j < CDIM/4; j += 256){
    int c = j*4;
    float4 w0 = *(const float4*)(cw + (size_t)(c+0)*4);
    float4 w1 = *(const float4*)(cw + (size_t)(c+1)*4);
    float4 w2 = *(const float4*)(cw + (size_t)(c+2)*4);
    float4 w3 = *(const float4*)(cw + (size_t)(c+3)*4);
    float4 acc = *(const float4*)(cb + c);
    #pragma unroll
    for (int k=0;k<4;k++){
      int tt = t - 3 + k;
      if (tt >= 0){
        float4 xv = *(const float4*)(base + (ptrdiff_t)(k-3)*DPROJ + c);
        acc.x = fmaf(xv.x, (&w0.x)[k], acc.x);
        acc.y = fmaf(xv.y, (&w1.x)[k], acc.y);
        acc.z = fmaf(xv.z, (&w2.x)[k], acc.z);
        acc.w = fmaf(xv.w, (&w3.x)[k], acc.w);
      }
    }
    acc.x=siluf(acc.x); acc.y=siluf(acc.y); acc.z=siluf(acc.z); acc.w=siluf(acc.w);
    *(float4*)(out + c) = acc;
  }
}

// ------------- dt=softplus(raw+bias); per-chunk cumsum of log(dA) ----------
__global__ __launch_bounds__(256) void k_dtcum(const float* __restrict__ ZX,
    const float* __restrict__ db0, const float* __restrict__ al0,
    const float* __restrict__ db1, const float* __restrict__ al1,
    float* __restrict__ DT, float* __restrict__ LAb){
  int idx = blockIdx.x*256 + threadIdx.x;
  if (idx >= 2*NH*NC) return;
  int d = idx >> 8, rem = idx & 255, h = rem >> 4, c = rem & 15;
  float bias = (d? db1: db0)[h];
  float eA   = __expf((d? al1: al0)[h]);
  float sum = 0.f;
  const float* zp = ZX + (size_t)d*L*DPROJ + (size_t)c*CQ*DPROJ + (DIN+CDIM) + h;
  float* dtp = DT + (size_t)d*L*NH + (size_t)c*CQ*NH + h;
  float* lap = LAb + (((size_t)d*NH + h)*NC + c)*CQ;
  for (int i=0;i<CQ;i++){
    float dtv = softplusf(zp[(size_t)i*DPROJ] + bias);
    dtp[(size_t)i*NH] = dtv;
    sum += -dtv*eA;
    lap[i] = sum;
  }
}

// ------------- scan step A: intra-chunk Y + chunk-state contribution -------
__global__ __launch_bounds__(256) void k_scanA(const float* __restrict__ XC,
    const float* __restrict__ DT, const float* __restrict__ LAb,
    float* __restrict__ Y, float* __restrict__ ZB){
  __shared__ __align__(16) float BT[64][64];   // phase1: B^T[n][j]; phase3: B row-major [j][n]
  __shared__ __align__(16) float CT[64][68];   // phase1: C^T[n][i]; phase2+: M^T[j][i]
  __shared__ __align__(16) float Xsh[64][68];  // X[j][p]
  __shared__ float lash[64], dtsh[64], wsh[64];
  int c = blockIdx.x, h = blockIdx.y, d = blockIdx.z;
  int tid = threadIdx.x;
  const float* xcb = XC + (size_t)d*L*CDIM + (size_t)c*CQ*CDIM;
  for (int idx=tid; idx<64*16; idx+=256){
    int row = idx>>4, q = idx&15, n = q*4;
    const float* rp = xcb + (size_t)row*CDIM;
    float4 xb = *(const float4*)(rp + DIN + n);
    float4 xc = *(const float4*)(rp + DIN + DST + n);
    float4 xx = *(const float4*)(rp + h*HD + n);
    BT[n][row]=xb.x; BT[n+1][row]=xb.y; BT[n+2][row]=xb.z; BT[n+3][row]=xb.w;
    CT[n][row]=xc.x; CT[n+1][row]=xc.y; CT[n+2][row]=xc.z; CT[n+3][row]=xc.w;
    Xsh[row][n]=xx.x; Xsh[row][n+1]=xx.y; Xsh[row][n+2]=xx.z; Xsh[row][n+3]=xx.w;
  }
  if (tid < 64){
    lash[tid] = LAb[(((size_t)d*NH+h)*NC+c)*CQ + tid];
    dtsh[tid] = DT[(size_t)d*L*NH + (size_t)(c*CQ+tid)*NH + h];
  }
  __syncthreads();
  if (tid < 64) wsh[tid] = __expf(lash[63]-lash[tid])*dtsh[tid];
  int tx = tid&15, ty = tid>>4;
  float g[4][4] = {};
  for (int n=0;n<64;n++){
    float4 cv = *(const float4*)(&CT[n][ty*4]);
    float4 bv = *(const float4*)(&BT[n][tx*4]);
    TILE_FMA(g, cv, bv);
  }
  float mm[4][4];
  #pragma unroll
  for (int a=0;a<4;a++){
    int i = ty*4+a; float li = lash[i];
    #pragma unroll
    for (int b2=0;b2<4;b2++){
      int j = tx*4+b2;
      mm[a][b2] = (j<=i) ? g[a][b2]*__expf(li-lash[j])*dtsh[j] : 0.f;
    }
  }
  __syncthreads();
  #pragma unroll
  for (int a=0;a<4;a++)
    #pragma unroll
    for (int b2=0;b2<4;b2++)
      CT[tx*4+b2][ty*4+a] = mm[a][b2];       // M^T[j][i]
  for (int idx=tid; idx<64*16; idx+=256){
    int row = idx>>4, q = idx&15, n = q*4;
    float4 xb = *(const float4*)(xcb + (size_t)row*CDIM + DIN + n);
    BT[row][n]=xb.x; BT[row][n+1]=xb.y; BT[row][n+2]=xb.z; BT[row][n+3]=xb.w;
  }
  __syncthreads();
  float yv[4][4] = {};
  for (int j=0;j<64;j++){
    float4 mv = *(const float4*)(&CT[j][ty*4]);
    float4 xv = *(const float4*)(&Xsh[j][tx*4]);
    TILE_FMA(yv, mv, xv);
  }
  float* yb = Y + (size_t)d*L*DIN + (size_t)c*CQ*DIN + (size_t)h*HD;
  #pragma unroll
  for (int a=0;a<4;a++){
    float4 o4 = make_float4(yv[a][0],yv[a][1],yv[a][2],yv[a][3]);
    *(float4*)(yb + (size_t)(ty*4+a)*DIN + tx*4) = o4;
  }
  float zz[4][4] = {};
  for (int j=0;j<64;j++){
    float w = wsh[j];
    float4 xv = *(const float4*)(&Xsh[j][ty*4]);
    float4 bv = *(const float4*)(&BT[j][tx*4]);
    float4 xw = make_float4(xv.x*w, xv.y*w, xv.z*w, xv.w*w);
    TILE_FMA(zz, xw, bv);
  }
  float* zb = ZB + (((size_t)d*NH+h)*NC + (size_t)c)*HD*DST;
  #pragma unroll
  for (int a=0;a<4;a++){
    float4 o4 = make_float4(zz[a][0],zz[a][1],zz[a][2],zz[a][3]);
    *(float4*)(zb + (size_t)(ty*4+a)*DST + tx*4) = o4;
  }
}

// ------------- scan step B: sequential chunk-state carry (16 steps) --------
#define UPD4(s,zv_) s.x=fmaf(s.x,ct,zv_.x); s.y=fmaf(s.y,ct,zv_.y); s.z=fmaf(s.z,ct,zv_.z); s.w=fmaf(s.w,ct,zv_.w);
__global__ __launch_bounds__(256) void k_scanB(const float* __restrict__ ZB,
    const float* __restrict__ LAb, float* __restrict__ SB){
  int h = blockIdx.x, d = blockIdx.y;
  int tid = threadIdx.x;
  int p = tid>>2, n0 = (tid&3)<<4;
  size_t hb = ((size_t)d*NH+h)*NC*HD*DST;
  size_t po = (size_t)p*DST + n0;
  const float* lap = LAb + ((size_t)d*NH+h)*NC*CQ;
  float4 s0=make_float4(0,0,0,0), s1=s0, s2=s0, s3=s0;
  for (int c=0;c<NC;c++){
    size_t off = hb + (size_t)c*HD*DST + po;
    *(float4*)(SB+off+0)  = s0;
    *(float4*)(SB+off+4)  = s1;
    *(float4*)(SB+off+8)  = s2;
    *(float4*)(SB+off+12) = s3;
    float ct = __expf(lap[c*CQ+63]);
    float4 z0 = *(const float4*)(ZB+off+0);
    float4 z1 = *(const float4*)(ZB+off+4);
    float4 z2 = *(const float4*)(ZB+off+8);
    float4 z3 = *(const float4*)(ZB+off+12);
    UPD4(s0,z0); UPD4(s1,z1); UPD4(s2,z2); UPD4(s3,z3);
  }
}

// ------------- scan step C: inter-chunk Y + D skip, into Y -----------------
__global__ __launch_bounds__(256) void k_scanC(const float* __restrict__ XC,
    const float* __restrict__ SB, const float* __restrict__ LAb,
    const float* __restrict__ D0, const float* __restrict__ D1,
    float* __restrict__ Y){
  __shared__ __align__(16) float CT[64][64];   // C^T[n][i]
  __shared__ __align__(16) float ST[64][68];   // S^T[n][p]
  __shared__ float lash[64];
  int c = blockIdx.x, h = blockIdx.y, d = blockIdx.z;
  int tid = threadIdx.x;
  const float* xcb = XC + (size_t)d*L*CDIM + (size_t)c*CQ*CDIM;
  const float* sb = SB + (((size_t)d*NH+h)*NC + (size_t)c)*HD*DST;
  for (int idx=tid; idx<64*16; idx+=256){
    int row = idx>>4, q = idx&15, n = q*4;
    float4 xc = *(const float4*)(xcb + (size_t)row*CDIM + DIN + DST + n);
    float4 sv = *(const float4*)(sb + (size_t)row*DST + n);
    CT[n][row]=xc.x; CT[n+1][row]=xc.y; CT[n+2][row]=xc.z; CT[n+3][row]=xc.w;
    ST[n][row]=sv.x; ST[n+1][row]=sv.y; ST[n+2][row]=sv.z; ST[n+3][row]=sv.w;
  }
  if (tid<64) lash[tid] = LAb[(((size_t)d*NH+h)*NC+c)*CQ + tid];
  __syncthreads();
  int tx=tid&15, ty=tid>>4;
  float acc[4][4] = {};
  for (int n=0;n<64;n++){
    float4 cv = *(const float4*)(&CT[n][ty*4]);
    float4 sv = *(const float4*)(&ST[n][tx*4]);
    TILE_FMA(acc, cv, sv);
  }
  float Dh = (d? D1 : D0)[h];
  float* yb = Y + (size_t)d*L*DIN + (size_t)c*CQ*DIN + (size_t)h*HD;
  #pragma unroll
  for (int a=0;a<4;a++){
    int i = ty*4+a;
    float el = __expf(lash[i]);
    float4 xv = *(const float4*)(xcb + (size_t)i*CDIM + h*HD + tx*4);
    float* yp = yb + (size_t)i*DIN + tx*4;
    float4 y4 = *(const float4*)yp;
    y4.x += el*acc[a][0] + Dh*xv.x;
    y4.y += el*acc[a][1] + Dh*xv.y;
    y4.z += el*acc[a][2] + Dh*xv.z;
    y4.w += el*acc[a][3] + Dh*xv.w;
    *(float4*)yp = y4;
  }
}

// ------------- gated RMSNorm -> fp32 (fallback) ----------------------------
__global__ __launch_bounds__(256) void k_rms(const float* __restrict__ Y,
    const float* __restrict__ ZX, const float* __restrict__ nw0,
    const float* __restrict__ nw1, float* __restrict__ XG){
  int r = blockIdx.x;
  int d = r >> 10;
  const float* nw = d? nw1 : nw0;
  int tid = threadIdx.x;
  float4 yv = *(const float4*)(Y + (size_t)r*DIN + tid*4);
  float4 zv = *(const float4*)(ZX + (size_t)r*DPROJ + tid*4);
  float4 gv;
  gv.x=yv.x*siluf(zv.x); gv.y=yv.y*siluf(zv.y);
  gv.z=yv.z*siluf(zv.z); gv.w=yv.w*siluf(zv.w);
  float q = gv.x*gv.x+gv.y*gv.y+gv.z*gv.z+gv.w*gv.w;
  #pragma unroll
  for (int o=1;o<64;o<<=1) q += __shfl_xor(q,o);
  __shared__ float sh[4];
  if ((tid&63)==0) sh[tid>>6] = q;
  __syncthreads();
  q = sh[0]+sh[1]+sh[2]+sh[3];
  float rs = rsqrtf(q*(1.f/DIN) + EPSV);
  float4 wv = *(const float4*)(nw + tid*4);
  float4 o4;
  o4.x=gv.x*rs*wv.x; o4.y=gv.y*rs*wv.y; o4.z=gv.z*rs*wv.z; o4.w=gv.w*rs*wv.w;
  *(float4*)(XG + (size_t)r*DIN + tid*4) = o4;
}

// ------------- gated RMSNorm -> split bf16 hi/lo (MFMA path) ---------------
__global__ __launch_bounds__(256) void k_rms_bf(const float* __restrict__ Y,
    const float* __restrict__ ZX, const float* __restrict__ nw0,
    const float* __restrict__ nw1, ushort* __restrict__ hi, ushort* __restrict__ lo){
  int r = blockIdx.x;
  int d = r >> 10;
  const float* nw = d? nw1 : nw0;
  int tid = threadIdx.x;
  float4 yv = *(const float4*)(Y + (size_t)r*DIN + tid*4);
  float4 zv = *(const float4*)(ZX + (size_t)r*DPROJ + tid*4);
  float4 gv;
  gv.x=yv.x*siluf(zv.x); gv.y=yv.y*siluf(zv.y);
  gv.z=yv.z*siluf(zv.z); gv.w=yv.w*siluf(zv.w);
  float q = gv.x*gv.x+gv.y*gv.y+gv.z*gv.z+gv.w*gv.w;
  #pragma unroll
  for (int o=1;o<64;o<<=1) q += __shfl_xor(q,o);
  __shared__ float sh[4];
  if ((tid&63)==0) sh[tid>>6] = q;
  __syncthreads();
  q = sh[0]+sh[1]+sh[2]+sh[3];
  float rs = rsqrtf(q*(1.f/DIN) + EPSV);
  float4 wv = *(const float4*)(nw + tid*4);
  float4 o4;
  o4.x=gv.x*rs*wv.x; o4.y=gv.y*rs*wv.y; o4.z=gv.z*rs*wv.z; o4.w=gv.w*rs*wv.w;
  ushort4 h4, l4;
  split2(o4.x,h4.x,l4.x); split2(o4.y,h4.y,l4.y);
  split2(o4.z,h4.z,l4.z); split2(o4.w,h4.w,l4.w);
  *(ushort4*)(hi + (size_t)r*DIN + tid*4) = h4;
  *(ushort4*)(lo + (size_t)r*DIN + tid*4) = l4;
}

// ------------- merged = [fwd[t], bwd[L-1-t]] (fp32 fallback) ---------------
__global__ __launch_bounds__(128) void k_merge(const float* __restrict__ X, float* __restrict__ MG){
  int t = blockIdx.x, tid = threadIdx.x;
  float4 f = *(const float4*)(X + (size_t)t*DM + tid*4);
  float4 b = *(const float4*)(X + (size_t)L*DM + (size_t)(L-1-t)*DM + tid*4);
  *(float4*)(MG + (size_t)t*2*DM + tid*4) = f;
  *(float4*)(MG + (size_t)t*2*DM + DM + tid*4) = b;
}

// ------------- merged -> split bf16 hi/lo (MFMA path) ----------------------
__global__ __launch_bounds__(128) void k_merge_bf(const float* __restrict__ X,
    ushort* __restrict__ hi, ushort* __restrict__ lo){
  int t = blockIdx.x, tid = threadIdx.x;
  float4 f = *(const float4*)(X + (size_t)t*DM + tid*4);
  float4 b = *(const float4*)(X + (size_t)L*DM + (size_t)(L-1-t)*DM + tid*4);
  ushort4 h4,l4;
  split2(f.x,h4.x,l4.x); split2(f.y,h4.y,l4.y); split2(f.z,h4.z,l4.z); split2(f.w,h4.w,l4.w);
  *(ushort4*)(hi + (size_t)t*2*DM + tid*4) = h4;
  *(ushort4*)(lo + (size_t)t*2*DM + tid*4) = l4;
  split2(b.x,h4.x,l4.x); split2(b.y,h4.y,l4.y); split2(b.z,h4.z,l4.z); split2(b.w,h4.w,l4.w);
  *(ushort4*)(hi + (size_t)t*2*DM + DM + tid*4) = h4;
  *(ushort4*)(lo + (size_t)t*2*DM + DM + tid*4) = l4;
}

extern "C" void kernel_launch(void* const* d_in, const int* in_sizes, int n_in,
                              void* d_out, int out_size, void* d_ws, size_t ws_size,
                              hipStream_t stream) {
  (void)in_sizes; (void)n_in; (void)out_size;
  const int*   tokens  = (const int*)d_in[0];
  const float* embedW  = (const float*)d_in[1];
  const float* f_in_proj = (const float*)d_in[2];
  const float* f_conv_w  = (const float*)d_in[3];
  const float* f_conv_b  = (const float*)d_in[4];
  const float* f_dt_bias = (const float*)d_in[5];
  const float* f_A_log   = (const float*)d_in[6];
  const float* f_D       = (const float*)d_in[7];
  const float* f_norm_w  = (const float*)d_in[8];
  const float* f_out_proj= (const float*)d_in[9];
  const float* f_ln_w    = (const float*)d_in[10];
  const float* f_ln_b    = (const float*)d_in[11];
  const float* b_in_proj = (const float*)d_in[12];
  const float* b_conv_w  = (const float*)d_in[13];
  const float* b_conv_b  = (const float*)d_in[14];
  const float* b_dt_bias = (const float*)d_in[15];
  const float* b_A_log   = (const float*)d_in[16];
  const float* b_D       = (const float*)d_in[17];
  const float* b_norm_w  = (const float*)d_in[18];
  const float* b_out_proj= (const float*)d_in[19];
  const float* b_ln_w    = (const float*)d_in[20];
  const float* b_ln_b    = (const float*)d_in[21];
  const float* mergeW    = (const float*)d_in[22];
  const float* fin_w     = (const float*)d_in[23];
  const float* fin_b     = (const float*)d_in[24];

  char* P = (char*)d_ws;
  // fp32 buffers (used by both paths; XN/XG/MG/FN only by fallback + XN reused)
  float* X  = (float*)P; P += (size_t)2*L*DM*4;
  float* XN = (float*)P; P += (size_t)2*L*DM*4;
  float* ZX = (float*)P; P += (size_t)2*L*DPROJ*4;
  float* XC = (float*)P; P += (size_t)2*L*CDIM*4;
  float* DTb= (float*)P; P += (size_t)2*L*NH*4;
  float* LAb= (float*)P; P += (size_t)2*NH*NC*CQ*4;
  float* Yb = (float*)P; P += (size_t)2*L*DIN*4;
  float* ZB = (float*)P; P += (size_t)2*NH*NC*HD*DST*4;
  float* SB = (float*)P; P += (size_t)2*NH*NC*HD*DST*4;
  float* XG = (float*)P; P += (size_t)2*L*DIN*4;
  float* MG = (float*)P; P += (size_t)L*2*DM*4;
  float* FN = (float*)P; P += (size_t)L*DM*4;
  // bf16 split buffers (MFMA path)
  ushort* XNh = (ushort*)P; P += (size_t)2*L*DM*2;
  ushort* XNl = (ushort*)P; P += (size_t)2*L*DM*2;
  ushort* XGh = (ushort*)P; P += (size_t)2*L*DIN*2;
  ushort* XGl = (ushort*)P; P += (size_t)2*L*DIN*2;
  ushort* MGh = (ushort*)P; P += (size_t)L*2*DM*2;
  ushort* MGl = (ushort*)P; P += (size_t)L*2*DM*2;
  ushort* FNh = (ushort*)P; P += (size_t)L*DM*2;
  ushort* FNl = (ushort*)P; P += (size_t)L*DM*2;
  ushort* WipH = (ushort*)P; P += (size_t)2*4*IPS*2;
  ushort* WipL = (ushort*)P; P += (size_t)2*4*IPS*2;
  ushort* WopH = (ushort*)P; P += (size_t)2*4*OPS*2;
  ushort* WopL = (ushort*)P; P += (size_t)2*4*OPS*2;
  ushort* WmgH = (ushort*)P; P += (size_t)DM*2*DM*2;
  ushort* WmgL = (ushort*)P; P += (size_t)DM*2*DM*2;
  ushort* WemH = (ushort*)P; P += (size_t)32000*DM*2;
  ushort* WemL = (ushort*)P; P += (size_t)32000*DM*2;
  size_t need = (size_t)(P - (char*)d_ws);
  bool mf = (ws_size >= need);

  k_embed<<<L,128,0,stream>>>(tokens, embedW, X);

  if (mf){
    // weight splits (every call; ws is re-poisoned by harness)
    k_split_ip<<<2304,256,0,stream>>>(f_in_proj, WipH, WipL);
    k_split_ip<<<2304,256,0,stream>>>(b_in_proj, WipH+(size_t)4*IPS, WipL+(size_t)4*IPS);
    k_split_flat<<<1024,256,0,stream>>>(f_out_proj, WopH, WopL, 262144);
    k_split_flat<<<1024,256,0,stream>>>(b_out_proj, WopH+(size_t)4*OPS, WopL+(size_t)4*OPS, 262144);
    k_split_flat<<<256,256,0,stream>>>(mergeW, WmgH, WmgL, 65536);
    k_split_flat<<<8000,256,0,stream>>>(embedW, WemH, WemL, 2048000);

    for (int i=0;i<4;i++){
      k_ln_bf<<<2*L,128,0,stream>>>(X, XNh, XNl, f_ln_w+i*DM, f_ln_b+i*DM, b_ln_w+i*DM, b_ln_b+i*DM, L);
      k_gemm_mf<128,128,0><<<dim3(18,16),256,0,stream>>>(
          XNh, XNl, WipH+(size_t)i*IPS, WipL+(size_t)i*IPS,
          WipH+(size_t)(4+i)*IPS, WipL+(size_t)(4+i)*IPS, 1024, ZX, DPROJ, DM);
      k_conv<<<2*L,256,0,stream>>>(ZX, f_conv_w+(size_t)i*CDIM*4, f_conv_b+(size_t)i*CDIM,
                                   b_conv_w+(size_t)i*CDIM*4, b_conv_b+(size_t)i*CDIM, XC);
      k_dtcum<<<2,256,0,stream>>>(ZX, f_dt_bias+i*NH, f_A_log+i*NH,
                                  b_dt_bias+i*NH, b_A_log+i*NH, DTb, LAb);
      k_scanA<<<dim3(NC,NH,2),256,0,stream>>>(XC, DTb, LAb, Yb, ZB);
      k_scanB<<<dim3(NH,2),256,0,stream>>>(ZB, LAb, SB);
      k_scanC<<<dim3(NC,NH,2),256,0,stream>>>(XC, SB, LAb, f_D+i*NH, b_D+i*NH, Yb);
      k_rms_bf<<<2*L,256,0,stream>>>(Yb, ZX, f_norm_w+i*DIN, b_norm_w+i*DIN, XGh, XGl);
      k_gemm_mf<64,64,1><<<dim3(8,32),256,0,stream>>>(
          XGh, XGl, WopH+(size_t)i*OPS, WopL+(size_t)i*OPS,
          WopH+(size_t)(4+i)*OPS, WopL+(size_t)(4+i)*OPS, 1024, X, DM, DIN);
    }
    k_merge_bf<<<L,128,0,stream>>>(X, MGh, MGl);
    k_gemm_mf<64,64,0><<<dim3(8,16),256,0,stream>>>(
        MGh, MGl, WmgH, WmgL, WmgH, WmgL, 1<<30, XN, DM, 2*DM);
    k_ln_bf<<<L,128,0,stream>>>(XN, FNh, FNl, fin_w, fin_b, fin_w, fin_b, L);
    k_gemm_mf<128,128,0><<<dim3(250,8),256,0,stream>>>(
        FNh, FNl, WemH, WemL, WemH, WemL, 1<<30, (float*)d_out, 32000, DM);
  } else {
    // fp32 fallback (round-5 verified pipeline)
    for (int i=0;i<4;i++){
      k_ln<<<2*L,128,0,stream>>>(X, XN, f_ln_w+i*DM, f_ln_b+i*DM, b_ln_w+i*DM, b_ln_b+i*DM, L);
      k_gemm<0><<<dim3((DPROJ+63)/64, (2*L)/64),256,0,stream>>>(
          XN, f_in_proj+(size_t)i*DPROJ*DM, b_in_proj+(size_t)i*DPROJ*DM, L,
          ZX, 2*L, DPROJ, DM);
      k_conv<<<2*L,256,0,stream>>>(ZX, f_conv_w+(size_t)i*CDIM*4, f_conv_b+(size_t)i*CDIM,
                                   b_conv_w+(size_t)i*CDIM*4, b_conv_b+(size_t)i*CDIM, XC);
      k_dtcum<<<2,256,0,stream>>>(ZX, f_dt_bias+i*NH, f_A_log+i*NH,
                                  b_dt_bias+i*NH, b_A_log+i*NH, DTb, LAb);
      k_scanA<<<dim3(NC,NH,2),256,0,stream>>>(XC, DTb, LAb, Yb, ZB);
      k_scanB<<<dim3(NH,2),256,0,stream>>>(ZB, LAb, SB);
      k_scanC<<<dim3(NC,NH,2),256,0,stream>>>(XC, SB, LAb, f_D+i*NH, b_D+i*NH, Yb);
      k_rms<<<2*L,256,0,stream>>>(Yb, ZX, f_norm_w+i*DIN, b_norm_w+i*DIN, XG);
      k_gemm<1><<<dim3(DM/64, (2*L)/64),256,0,stream>>>(
          XG, f_out_proj+(size_t)i*DM*DIN, b_out_proj+(size_t)i*DM*DIN, L,
          X, 2*L, DM, DIN);
    }
    k_merge<<<L,128,0,stream>>>(X, MG);
    k_gemm<0><<<dim3(DM/64, L/64),256,0,stream>>>(MG, mergeW, mergeW, 1<<30, XN, L, DM, 2*DM);
    k_ln<<<L,128,0,stream>>>(XN, FN, fin_w, fin_b, fin_w, fin_b, L);
    k_gemm<0><<<dim3(32000/64, L/64),256,0,stream>>>(FN, embedW, embedW, 1<<30,
        (float*)d_out, L, 32000, DM);
  }
}

// Round 11
// 841.071 us; speedup vs baseline: 2.0412x; 1.2773x over previous
//
#include <hip/hip_runtime.h>
#include <math.h>

#define L      1024
#define DM     512
#define DIN    1024
#define NH     16
#define HD     64
#define DST    64
#define CDIM   1152
#define DPROJ  2192
#define NC     16
#define CQ     64
#define EPSV   1e-5f
#define SQRTD  22.62741699796952f

#define IPS (2304*512)   // padded in_proj weights per (dir,layer)
#define OPS (512*1024)

typedef short short8v __attribute__((ext_vector_type(8)));
typedef float f32x4 __attribute__((ext_vector_type(4)));

__device__ __forceinline__ float siluf(float x){ return x/(1.f+__expf(-x)); }
__device__ __forceinline__ float softplusf(float x){ return (x>20.f)? x : log1pf(__expf(x)); }

__device__ __forceinline__ ushort bf16_rne(float f){
  union { float f; unsigned u; } v; v.f = f;
  unsigned u = v.u;
  return (ushort)((u + 0x7FFFu + ((u>>16)&1u)) >> 16);
}
__device__ __forceinline__ float bf16_f(ushort h){
  union { unsigned u; float f; } v; v.u = ((unsigned)h)<<16;
  return v.f;
}
__device__ __forceinline__ void split2(float x, ushort& hi, ushort& lo){
  ushort h = bf16_rne(x);
  hi = h;
  lo = bf16_rne(x - bf16_f(h));
}

// async global->LDS, 16B per lane (dest must be linear: base + lane*16)
#define GLOAD16(g, l) __builtin_amdgcn_global_load_lds( \
    (const __attribute__((address_space(1))) void*)(g), \
    (__attribute__((address_space(3))) void*)(l), 16, 0, 0)

#define TILE_FMA(acc, av, bv) do { \
  acc[0][0]=fmaf(av.x,bv.x,acc[0][0]); acc[0][1]=fmaf(av.x,bv.y,acc[0][1]); \
  acc[0][2]=fmaf(av.x,bv.z,acc[0][2]); acc[0][3]=fmaf(av.x,bv.w,acc[0][3]); \
  acc[1][0]=fmaf(av.y,bv.x,acc[1][0]); acc[1][1]=fmaf(av.y,bv.y,acc[1][1]); \
  acc[1][2]=fmaf(av.y,bv.z,acc[1][2]); acc[1][3]=fmaf(av.y,bv.w,acc[1][3]); \
  acc[2][0]=fmaf(av.z,bv.x,acc[2][0]); acc[2][1]=fmaf(av.z,bv.y,acc[2][1]); \
  acc[2][2]=fmaf(av.z,bv.z,acc[2][2]); acc[2][3]=fmaf(av.z,bv.w,acc[2][3]); \
  acc[3][0]=fmaf(av.w,bv.x,acc[3][0]); acc[3][1]=fmaf(av.w,bv.y,acc[3][1]); \
  acc[3][2]=fmaf(av.w,bv.z,acc[3][2]); acc[3][3]=fmaf(av.w,bv.w,acc[3][3]); \
} while(0)

// ---------------- embedding (+ reversed copy for bwd chain) ----------------
__global__ __launch_bounds__(128) void k_embed(const int* __restrict__ tok,
    const float* __restrict__ W, float* __restrict__ X){
  int t = blockIdx.x, tid = threadIdx.x;
  int token = tok[t];
  float4 v = *(const float4*)(W + (size_t)token*DM + tid*4);
  v.x*=SQRTD; v.y*=SQRTD; v.z*=SQRTD; v.w*=SQRTD;
  *(float4*)(X + (size_t)t*DM + tid*4) = v;
  *(float4*)(X + (size_t)L*DM + (size_t)(L-1-t)*DM + tid*4) = v;
}

// ---------------- layernorm over 512 -> fp32 (fallback path) ---------------
__global__ __launch_bounds__(128) void k_ln(const float* __restrict__ src, float* __restrict__ dst,
    const float* __restrict__ w0, const float* __restrict__ b0,
    const float* __restrict__ w1, const float* __restrict__ b1, int rows_per_dir){
  int r = blockIdx.x, tid = threadIdx.x;
  const float* w  = (r<rows_per_dir)? w0 : w1;
  const float* bb = (r<rows_per_dir)? b0 : b1;
  float4 v = *(const float4*)(src + (size_t)r*DM + tid*4);
  float s = v.x+v.y+v.z+v.w;
  float q = v.x*v.x+v.y*v.y+v.z*v.z+v.w*v.w;
  #pragma unroll
  for (int o=1;o<64;o<<=1){ s += __shfl_xor(s,o); q += __shfl_xor(q,o); }
  __shared__ float sh[4];
  if ((tid&63)==0){ sh[(tid>>6)*2]=s; sh[(tid>>6)*2+1]=q; }
  __syncthreads();
  s = sh[0]+sh[2]; q = sh[1]+sh[3];
  float m = s*(1.f/DM);
  float rs = rsqrtf(q*(1.f/DM) - m*m + EPSV);
  float4 wv = *(const float4*)(w + tid*4);
  float4 bv = *(const float4*)(bb + tid*4);
  float4 o4;
  o4.x=(v.x-m)*rs*wv.x+bv.x; o4.y=(v.y-m)*rs*wv.y+bv.y;
  o4.z=(v.z-m)*rs*wv.z+bv.z; o4.w=(v.w-m)*rs*wv.w+bv.w;
  *(float4*)(dst + (size_t)r*DM + tid*4) = o4;
}

// ---------------- layernorm -> split bf16 hi/lo (MFMA path) ----------------
__global__ __launch_bounds__(128) void k_ln_bf(const float* __restrict__ src,
    ushort* __restrict__ hi, ushort* __restrict__ lo,
    const float* __restrict__ w0, const float* __restrict__ b0,
    const float* __restrict__ w1, const float* __restrict__ b1, int rows_per_dir){
  int r = blockIdx.x, tid = threadIdx.x;
  const float* w  = (r<rows_per_dir)? w0 : w1;
  const float* bb = (r<rows_per_dir)? b0 : b1;
  float4 v = *(const float4*)(src + (size_t)r*DM + tid*4);
  float s = v.x+v.y+v.z+v.w;
  float q = v.x*v.x+v.y*v.y+v.z*v.z+v.w*v.w;
  #pragma unroll
  for (int o=1;o<64;o<<=1){ s += __shfl_xor(s,o); q += __shfl_xor(q,o); }
  __shared__ float sh[4];
  if ((tid&63)==0){ sh[(tid>>6)*2]=s; sh[(tid>>6)*2+1]=q; }
  __syncthreads();
  s = sh[0]+sh[2]; q = sh[1]+sh[3];
  float m = s*(1.f/DM);
  float rs = rsqrtf(q*(1.f/DM) - m*m + EPSV);
  float4 wv = *(const float4*)(w + tid*4);
  float4 bv = *(const float4*)(bb + tid*4);
  float4 o4;
  o4.x=(v.x-m)*rs*wv.x+bv.x; o4.y=(v.y-m)*rs*wv.y+bv.y;
  o4.z=(v.z-m)*rs*wv.z+bv.z; o4.w=(v.w-m)*rs*wv.w+bv.w;
  ushort4 h4, l4;
  split2(o4.x,h4.x,l4.x); split2(o4.y,h4.y,l4.y);
  split2(o4.z,h4.z,l4.z); split2(o4.w,h4.w,l4.w);
  *(ushort4*)(hi + (size_t)r*DM + tid*4) = h4;
  *(ushort4*)(lo + (size_t)r*DM + tid*4) = l4;
}

// ---------------- fp32 NT GEMM (fallback path) -----------------------------
template<int RES>
__global__ __launch_bounds__(256) void k_gemm(const float* __restrict__ A,
    const float* __restrict__ B0, const float* __restrict__ B1, int msplit,
    float* __restrict__ C, int M, int N, int K){
  __shared__ __align__(16) float As[16][68];
  __shared__ __align__(16) float Bs[16][68];
  int n0 = blockIdx.x*64, m0 = blockIdx.y*64;
  const float* Bp = (m0 >= msplit) ? B1 : B0;
  int tid = threadIdx.x;
  int lm = tid>>2, lk = (tid&3)<<2;
  int tx = tid&15, ty = tid>>4;
  float acc[4][4] = {};
  const float* Ap = A + (size_t)(m0+lm)*K + lk;
  bool bval = (n0+lm) < N;
  const float* Bq = Bp + (size_t)(n0+lm)*K + lk;
  for (int k0=0;k0<K;k0+=16){
    float4 a = *(const float4*)(Ap + k0);
    float4 b = bval ? *(const float4*)(Bq + k0) : make_float4(0.f,0.f,0.f,0.f);
    As[lk+0][lm]=a.x; As[lk+1][lm]=a.y; As[lk+2][lm]=a.z; As[lk+3][lm]=a.w;
    Bs[lk+0][lm]=b.x; Bs[lk+1][lm]=b.y; Bs[lk+2][lm]=b.z; Bs[lk+3][lm]=b.w;
    __syncthreads();
    #pragma unroll
    for (int k=0;k<16;k++){
      float4 av = *(const float4*)(&As[k][ty*4]);
      float4 bv = *(const float4*)(&Bs[k][tx*4]);
      TILE_FMA(acc, av, bv);
    }
    __syncthreads();
  }
  if (n0 + tx*4 < N){
    #pragma unroll
    for (int i2=0;i2<4;i2++){
      float* cp = C + (size_t)(m0+ty*4+i2)*N + n0 + tx*4;
      float4 o4;
      if (RES){
        float4 c4 = *(const float4*)cp;
        o4.x=c4.x+acc[i2][0]; o4.y=c4.y+acc[i2][1];
        o4.z=c4.z+acc[i2][2]; o4.w=c4.w+acc[i2][3];
      } else {
        o4.x=acc[i2][0]; o4.y=acc[i2][1]; o4.z=acc[i2][2]; o4.w=acc[i2][3];
      }
      *(float4*)cp = o4;
    }
  }
}

// ---------------- split-bf16 MFMA NT GEMM: C[M,Nt] (+=) A * B^T ------------
// XCD-bijective swizzle (T1): tiles laid n-fastest; XCD k gets a contiguous
// m-tile range and streams B once (requires nwg%8==0 — all our grids comply).
template<int TM, int TN, int RES>
__global__ __launch_bounds__(256) void k_gemm_mf(
    const ushort* __restrict__ Ah, const ushort* __restrict__ Al,
    const ushort* __restrict__ Bh0, const ushort* __restrict__ Bl0,
    const ushort* __restrict__ Bh1, const ushort* __restrict__ Bl1,
    int msplit, float* __restrict__ C, int Ntrue, int K){
  constexpr int WGM = (TM==128)?2:1;
  constexpr int WGN = 4/WGM;
  constexpr int TMW = TM/WGM, TNW = TN/WGN;
  constexpr int FM = TMW/16, FN = TNW/16;
  __shared__ ushort sAh[TM*64], sAl[TM*64], sBh[TN*64], sBl[TN*64];
  int tid = threadIdx.x, lane = tid&63, wid = tid>>6;
  int wm = (wid/WGN)*TMW, wn = (wid%WGN)*TNW;
  int lrow = lane&15, kg = lane>>4;
  int gx = gridDim.x, nwg = gx*gridDim.y;
  int lin = blockIdx.y*gx + blockIdx.x;
  int cpx = nwg >> 3;
  int swz = (lin & 7)*cpx + (lin >> 3);
  int m0 = (swz / gx)*TM, n0 = (swz % gx)*TN;
  const ushort* Bh = (m0>=msplit)? Bh1 : Bh0;
  const ushort* Bl = (m0>=msplit)? Bl1 : Bl0;
  f32x4 acc[FM][FN] = {};
  for (int k0=0;k0<K;k0+=64){
    #pragma unroll
    for (int i=0;i<TM/32;i++){
      int off=(i*256+tid)*8, r=off>>6, cc=off&63;
      size_t gs=(size_t)(m0+r)*K + k0 + cc;
      GLOAD16(Ah+gs, &sAh[off]);
      GLOAD16(Al+gs, &sAl[off]);
    }
    #pragma unroll
    for (int i=0;i<TN/32;i++){
      int off=(i*256+tid)*8, r=off>>6, cc=off&63;
      size_t gs=(size_t)(n0+r)*K + k0 + cc;
      GLOAD16(Bh+gs, &sBh[off]);
      GLOAD16(Bl+gs, &sBl[off]);
    }
    __syncthreads();
    #pragma unroll
    for (int kk=0;kk<2;kk++){
      short8v av_h[FM], av_l[FM], bv_h[FN], bv_l[FN];
      #pragma unroll
      for (int f=0;f<FM;f++){
        int o=(wm+f*16+lrow)*64 + kk*32 + kg*8;
        av_h[f]=*(const short8v*)&sAh[o];
        av_l[f]=*(const short8v*)&sAl[o];
      }
      #pragma unroll
      for (int f=0;f<FN;f++){
        int o=(wn+f*16+lrow)*64 + kk*32 + kg*8;
        bv_h[f]=*(const short8v*)&sBh[o];
        bv_l[f]=*(const short8v*)&sBl[o];
      }
      #pragma unroll
      for (int fm=0;fm<FM;fm++)
        #pragma unroll
        for (int fn=0;fn<FN;fn++){
          acc[fm][fn]=__builtin_amdgcn_mfma_f32_16x16x32_bf16(av_h[fm],bv_h[fn],acc[fm][fn],0,0,0);
          acc[fm][fn]=__builtin_amdgcn_mfma_f32_16x16x32_bf16(av_h[fm],bv_l[fn],acc[fm][fn],0,0,0);
          acc[fm][fn]=__builtin_amdgcn_mfma_f32_16x16x32_bf16(av_l[fm],bv_h[fn],acc[fm][fn],0,0,0);
        }
    }
    __syncthreads();
  }
  // C/D layout (m89-verified): col = lane&15, row = (lane>>4)*4 + reg
  #pragma unroll
  for (int fm=0;fm<FM;fm++)
    #pragma unroll
    for (int fn=0;fn<FN;fn++){
      int col = n0 + wn + fn*16 + lrow;
      if (col < Ntrue){
        #pragma unroll
        for (int r=0;r<4;r++){
          int row = m0 + wm + fm*16 + kg*4 + r;
          float* cp = C + (size_t)row*Ntrue + col;
          float v = acc[fm][fn][r];
          *cp = RES ? (*cp + v) : v;
        }
      }
    }
}

// ---------------- weight split kernels -------------------------------------
__global__ __launch_bounds__(256) void k_split_flat(const float* __restrict__ src,
    ushort* __restrict__ hi, ushort* __restrict__ lo, int n8){
  int i = blockIdx.x*256 + threadIdx.x;
  if (i >= n8) return;
  size_t e0 = (size_t)i*8;
  float4 v0 = *(const float4*)(src+e0);
  float4 v1 = *(const float4*)(src+e0+4);
  ushort4 h0,l0,h1,l1;
  split2(v0.x,h0.x,l0.x); split2(v0.y,h0.y,l0.y); split2(v0.z,h0.z,l0.z); split2(v0.w,h0.w,l0.w);
  split2(v1.x,h1.x,l1.x); split2(v1.y,h1.y,l1.y); split2(v1.z,h1.z,l1.z); split2(v1.w,h1.w,l1.w);
  *(ushort4*)(hi+e0)=h0; *(ushort4*)(hi+e0+4)=h1;
  *(ushort4*)(lo+e0)=l0; *(ushort4*)(lo+e0+4)=l1;
}

// in_proj: [4][2192][512] -> padded [4][2304][512], zero-filled pad rows
__global__ __launch_bounds__(256) void k_split_ip(const float* __restrict__ src,
    ushort* __restrict__ hi, ushort* __restrict__ lo){
  int i = blockIdx.x*256 + threadIdx.x;     // grid covers 4*2304*512/8 exactly
  size_t e0 = (size_t)i*8;
  int row = (int)(e0>>9), col = (int)(e0&511);
  int layer = row/2304, rr = row - layer*2304;
  ushort4 h0={0,0,0,0}, l0={0,0,0,0}, h1={0,0,0,0}, l1={0,0,0,0};
  if (rr < 2192){
    const float* sp = src + ((size_t)(layer*2192+rr)<<9) + col;
    float4 v0 = *(const float4*)(sp);
    float4 v1 = *(const float4*)(sp+4);
    split2(v0.x,h0.x,l0.x); split2(v0.y,h0.y,l0.y); split2(v0.z,h0.z,l0.z); split2(v0.w,h0.w,l0.w);
    split2(v1.x,h1.x,l1.x); split2(v1.y,h1.y,l1.y); split2(v1.z,h1.z,l1.z); split2(v1.w,h1.w,l1.w);
  }
  *(ushort4*)(hi+e0)=h0; *(ushort4*)(hi+e0+4)=h1;
  *(ushort4*)(lo+e0)=l0; *(ushort4*)(lo+e0+4)=l1;
}

// ------- fused: causal depthwise conv(4)+silu  AND  wave-parallel dtcum ----
// blocks [0,2048): conv rows; blocks [2048,2176): dt softplus + prefix scan.
__global__ __launch_bounds__(256) void k_convdt(const float* __restrict__ ZX,
    const float* __restrict__ cw0, const float* __restrict__ cb0,
    const float* __restrict__ cw1, const float* __restrict__ cb1,
    float* __restrict__ XC,
    const float* __restrict__ db0, const float* __restrict__ al0,
    const float* __restrict__ db1, const float* __restrict__ al1,
    float* __restrict__ DT, float* __restrict__ LAb){
  int tid = threadIdx.x;
  if (blockIdx.x < 2*L){
    int r = blockIdx.x;            // d*L + t
    int d = r >> 10, t = r & (L-1);
    const float* cw = d ? cw1 : cw0;
    const float* cb = d ? cb1 : cb0;
    const float* base = ZX + (size_t)r*DPROJ + DIN;
    float* out = XC + (size_t)r*CDIM;
    for (int j = tid; j < CDIM/4; j += 256){
      int c = j*4;
      float4 w0 = *(const float4*)(cw + (size_t)(c+0)*4);
      float4 w1 = *(const float4*)(cw + (size_t)(c+1)*4);
      float4 w2 = *(const float4*)(cw + (size_t)(c+2)*4);
      float4 w3 = *(const float4*)(cw + (size_t)(c+3)*4);
      float4 acc = *(const float4*)(cb + c);
      #pragma unroll
      for (int k=0;k<4;k++){
        int tt = t - 3 + k;
        if (tt >= 0){
          float4 xv = *(const float4*)(base + (ptrdiff_t)(k-3)*DPROJ + c);
          acc.x = fmaf(xv.x, (&w0.x)[k], acc.x);
          acc.y = fmaf(xv.y, (&w1.x)[k], acc.y);
          acc.z = fmaf(xv.z, (&w2.x)[k], acc.z);
          acc.w = fmaf(xv.w, (&w3.x)[k], acc.w);
        }
      }
      acc.x=siluf(acc.x); acc.y=siluf(acc.y); acc.z=siluf(acc.z); acc.w=siluf(acc.w);
      *(float4*)(out + c) = acc;
    }
  } else {
    // one wave per (d,h,c): 512 waves total
    int lid = tid & 63, wv = tid >> 6;
    int gid = (blockIdx.x - 2*L)*4 + wv;      // 0..511
    int d = gid >> 8, rem = gid & 255, h = rem >> 4, c = rem & 15;
    float bias = (d? db1: db0)[h];
    float eA   = __expf((d? al1: al0)[h]);
    const float* zp = ZX + (size_t)d*L*DPROJ + (size_t)(c*CQ+lid)*DPROJ + (DIN+CDIM) + h;
    float dtv = softplusf(*zp + bias);
    DT[(size_t)d*L*NH + (size_t)(c*CQ+lid)*NH + h] = dtv;
    float sc = -dtv*eA;
    #pragma unroll
    for (int o=1;o<64;o<<=1){
      float t2 = __shfl_up(sc, o);
      if (lid >= o) sc += t2;
    }
    LAb[(((size_t)d*NH+h)*NC+c)*CQ + lid] = sc;
  }
}

// ------------- scan step A: intra-chunk Y + chunk-state contribution -------
__global__ __launch_bounds__(256) void k_scanA(const float* __restrict__ XC,
    const float* __restrict__ DT, const float* __restrict__ LAb,
    float* __restrict__ Y, float* __restrict__ ZB){
  __shared__ __align__(16) float BT[64][64];   // phase1: B^T[n][j]; phase3: B row-major [j][n]
  __shared__ __align__(16) float CT[64][68];   // phase1: C^T[n][i]; phase2+: M^T[j][i]
  __shared__ __align__(16) float Xsh[64][68];  // X[j][p]
  __shared__ float lash[64], dtsh[64], wsh[64];
  int c = blockIdx.x, h = blockIdx.y, d = blockIdx.z;
  int tid = threadIdx.x;
  const float* xcb = XC + (size_t)d*L*CDIM + (size_t)c*CQ*CDIM;
  for (int idx=tid; idx<64*16; idx+=256){
    int row = idx>>4, q = idx&15, n = q*4;
    const float* rp = xcb + (size_t)row*CDIM;
    float4 xb = *(const float4*)(rp + DIN + n);
    float4 xc = *(const float4*)(rp + DIN + DST + n);
    float4 xx = *(const float4*)(rp + h*HD + n);
    BT[n][row]=xb.x; BT[n+1][row]=xb.y; BT[n+2][row]=xb.z; BT[n+3][row]=xb.w;
    CT[n][row]=xc.x; CT[n+1][row]=xc.y; CT[n+2][row]=xc.z; CT[n+3][row]=xc.w;
    Xsh[row][n]=xx.x; Xsh[row][n+1]=xx.y; Xsh[row][n+2]=xx.z; Xsh[row][n+3]=xx.w;
  }
  if (tid < 64){
    lash[tid] = LAb[(((size_t)d*NH+h)*NC+c)*CQ + tid];
    dtsh[tid] = DT[(size_t)d*L*NH + (size_t)(c*CQ+tid)*NH + h];
  }
  __syncthreads();
  if (tid < 64) wsh[tid] = __expf(lash[63]-lash[tid])*dtsh[tid];
  int tx = tid&15, ty = tid>>4;
  float g[4][4] = {};
  for (int n=0;n<64;n++){
    float4 cv = *(const float4*)(&CT[n][ty*4]);
    float4 bv = *(const float4*)(&BT[n][tx*4]);
    TILE_FMA(g, cv, bv);
  }
  float mm[4][4];
  #pragma unroll
  for (int a=0;a<4;a++){
    int i = ty*4+a; float li = lash[i];
    #pragma unroll
    for (int b2=0;b2<4;b2++){
      int j = tx*4+b2;
      mm[a][b2] = (j<=i) ? g[a][b2]*__expf(li-lash[j])*dtsh[j] : 0.f;
    }
  }
  __syncthreads();
  #pragma unroll
  for (int a=0;a<4;a++)
    #pragma unroll
    for (int b2=0;b2<4;b2++)
      CT[tx*4+b2][ty*4+a] = mm[a][b2];       // M^T[j][i]
  for (int idx=tid; idx<64*16; idx+=256){
    int row = idx>>4, q = idx&15, n = q*4;
    float4 xb = *(const float4*)(xcb + (size_t)row*CDIM + DIN + n);
    BT[row][n]=xb.x; BT[row][n+1]=xb.y; BT[row][n+2]=xb.z; BT[row][n+3]=xb.w;
  }
  __syncthreads();
  float yv[4][4] = {};
  for (int j=0;j<64;j++){
    float4 mv = *(const float4*)(&CT[j][ty*4]);
    float4 xv = *(const float4*)(&Xsh[j][tx*4]);
    TILE_FMA(yv, mv, xv);
  }
  float* yb = Y + (size_t)d*L*DIN + (size_t)c*CQ*DIN + (size_t)h*HD;
  #pragma unroll
  for (int a=0;a<4;a++){
    float4 o4 = make_float4(yv[a][0],yv[a][1],yv[a][2],yv[a][3]);
    *(float4*)(yb + (size_t)(ty*4+a)*DIN + tx*4) = o4;
  }
  float zz[4][4] = {};
  for (int j=0;j<64;j++){
    float w = wsh[j];
    float4 xv = *(const float4*)(&Xsh[j][ty*4]);
    float4 bv = *(const float4*)(&BT[j][tx*4]);
    float4 xw = make_float4(xv.x*w, xv.y*w, xv.z*w, xv.w*w);
    TILE_FMA(zz, xw, bv);
  }
  float* zb = ZB + (((size_t)d*NH+h)*NC + (size_t)c)*HD*DST;
  #pragma unroll
  for (int a=0;a<4;a++){
    float4 o4 = make_float4(zz[a][0],zz[a][1],zz[a][2],zz[a][3]);
    *(float4*)(zb + (size_t)(ty*4+a)*DST + tx*4) = o4;
  }
}

// ------------- scan step B: chunk-state carry, 4x parallel slices ----------
__global__ __launch_bounds__(256) void k_scanB(const float* __restrict__ ZB,
    const float* __restrict__ LAb, float* __restrict__ SB){
  int h = blockIdx.x, d = blockIdx.y, q = blockIdx.z;   // q: 16-row slice
  int tid = threadIdx.x;
  int r = q*16 + (tid>>4), col = (tid&15)*4;
  size_t hb = ((size_t)d*NH+h)*NC*HD*DST;
  size_t po = (size_t)r*DST + col;
  const float* lap = LAb + ((size_t)d*NH+h)*NC*CQ;
  float4 s = make_float4(0.f,0.f,0.f,0.f);
  for (int c=0;c<NC;c++){
    size_t off = hb + (size_t)c*HD*DST + po;
    *(float4*)(SB+off) = s;
    float ct = __expf(lap[c*CQ+63]);
    float4 z = *(const float4*)(ZB+off);
    s.x=fmaf(s.x,ct,z.x); s.y=fmaf(s.y,ct,z.y);
    s.z=fmaf(s.z,ct,z.z); s.w=fmaf(s.w,ct,z.w);
  }
}

// ------------- scan step C: inter-chunk Y + D skip, into Y -----------------
__global__ __launch_bounds__(256) void k_scanC(const float* __restrict__ XC,
    const float* __restrict__ SB, const float* __restrict__ LAb,
    const float* __restrict__ D0, const float* __restrict__ D1,
    float* __restrict__ Y){
  __shared__ __align__(16) float CT[64][64];   // C^T[n][i]
  __shared__ __align__(16) float ST[64][68];   // S^T[n][p]
  __shared__ float lash[64];
  int c = blockIdx.x, h = blockIdx.y, d = blockIdx.z;
  int tid = threadIdx.x;
  const float* xcb = XC + (size_t)d*L*CDIM + (size_t)c*CQ*CDIM;
  const float* sb = SB + (((size_t)d*NH+h)*NC + (size_t)c)*HD*DST;
  for (int idx=tid; idx<64*16; idx+=256){
    int row = idx>>4, q = idx&15, n = q*4;
    float4 xc = *(const float4*)(xcb + (size_t)row*CDIM + DIN + DST + n);
    float4 sv = *(const float4*)(sb + (size_t)row*DST + n);
    CT[n][row]=xc.x; CT[n+1][row]=xc.y; CT[n+2][row]=xc.z; CT[n+3][row]=xc.w;
    ST[n][row]=sv.x; ST[n+1][row]=sv.y; ST[n+2][row]=sv.z; ST[n+3][row]=sv.w;
  }
  if (tid<64) lash[tid] = LAb[(((size_t)d*NH+h)*NC+c)*CQ + tid];
  __syncthreads();
  int tx=tid&15, ty=tid>>4;
  float acc[4][4] = {};
  for (int n=0;n<64;n++){
    float4 cv = *(const float4*)(&CT[n][ty*4]);
    float4 sv = *(const float4*)(&ST[n][tx*4]);
    TILE_FMA(acc, cv, sv);
  }
  float Dh = (d? D1 : D0)[h];
  float* yb = Y + (size_t)d*L*DIN + (size_t)c*CQ*DIN + (size_t)h*HD;
  #pragma unroll
  for (int a=0;a<4;a++){
    int i = ty*4+a;
    float el = __expf(lash[i]);
    float4 xv = *(const float4*)(xcb + (size_t)i*CDIM + h*HD + tx*4);
    float* yp = yb + (size_t)i*DIN + tx*4;
    float4 y4 = *(const float4*)yp;
    y4.x += el*acc[a][0] + Dh*xv.x;
    y4.y += el*acc[a][1] + Dh*xv.y;
    y4.z += el*acc[a][2] + Dh*xv.z;
    y4.w += el*acc[a][3] + Dh*xv.w;
    *(float4*)yp = y4;
  }
}

// ------------- gated RMSNorm -> fp32 (fallback) ----------------------------
__global__ __launch_bounds__(256) void k_rms(const float* __restrict__ Y,
    const float* __restrict__ ZX, const float* __restrict__ nw0,
    const float* __restrict__ nw1, float* __restrict__ XG){
  int r = blockIdx.x;
  int d = r >> 10;
  const float* nw = d? nw1 : nw0;
  int tid = threadIdx.x;
  float4 yv = *(const float4*)(Y + (size_t)r*DIN + tid*4);
  float4 zv = *(const float4*)(ZX + (size_t)r*DPROJ + tid*4);
  float4 gv;
  gv.x=yv.x*siluf(zv.x); gv.y=yv.y*siluf(zv.y);
  gv.z=yv.z*siluf(zv.z); gv.w=yv.w*siluf(zv.w);
  float q = gv.x*gv.x+gv.y*gv.y+gv.z*gv.z+gv.w*gv.w;
  #pragma unroll
  for (int o=1;o<64;o<<=1) q += __shfl_xor(q,o);
  __shared__ float sh[4];
  if ((tid&63)==0) sh[tid>>6] = q;
  __syncthreads();
  q = sh[0]+sh[1]+sh[2]+sh[3];
  float rs = rsqrtf(q*(1.f/DIN) + EPSV);
  float4 wv = *(const float4*)(nw + tid*4);
  float4 o4;
  o4.x=gv.x*rs*wv.x; o4.y=gv.y*rs*wv.y; o4.z=gv.z*rs*wv.z; o4.w=gv.w*rs*wv.w;
  *(float4*)(XG + (size_t)r*DIN + tid*4) = o4;
}

// ------------- gated RMSNorm -> split bf16 hi/lo (MFMA path) ---------------
__global__ __launch_bounds__(256) void k_rms_bf(const float* __restrict__ Y,
    const float* __restrict__ ZX, const float* __restrict__ nw0,
    const float* __restrict__ nw1, ushort* __restrict__ hi, ushort* __restrict__ lo){
  int r = blockIdx.x;
  int d = r >> 10;
  const float* nw = d? nw1 : nw0;
  int tid = threadIdx.x;
  float4 yv = *(const float4*)(Y + (size_t)r*DIN + tid*4);
  float4 zv = *(const float4*)(ZX + (size_t)r*DPROJ + tid*4);
  float4 gv;
  gv.x=yv.x*siluf(zv.x); gv.y=yv.y*siluf(zv.y);
  gv.z=yv.z*siluf(zv.z); gv.w=yv.w*siluf(zv.w);
  float q = gv.x*gv.x+gv.y*gv.y+gv.z*gv.z+gv.w*gv.w;
  #pragma unroll
  for (int o=1;o<64;o<<=1) q += __shfl_xor(q,o);
  __shared__ float sh[4];
  if ((tid&63)==0) sh[tid>>6] = q;
  __syncthreads();
  q = sh[0]+sh[1]+sh[2]+sh[3];
  float rs = rsqrtf(q*(1.f/DIN) + EPSV);
  float4 wv = *(const float4*)(nw + tid*4);
  float4 o4;
  o4.x=gv.x*rs*wv.x; o4.y=gv.y*rs*wv.y; o4.z=gv.z*rs*wv.z; o4.w=gv.w*rs*wv.w;
  ushort4 h4, l4;
  split2(o4.x,h4.x,l4.x); split2(o4.y,h4.y,l4.y);
  split2(o4.z,h4.z,l4.z); split2(o4.w,h4.w,l4.w);
  *(ushort4*)(hi + (size_t)r*DIN + tid*4) = h4;
  *(ushort4*)(lo + (size_t)r*DIN + tid*4) = l4;
}

// ------------- merged = [fwd[t], bwd[L-1-t]] (fp32 fallback) ---------------
__global__ __launch_bounds__(128) void k_merge(const float* __restrict__ X, float* __restrict__ MG){
  int t = blockIdx.x, tid = threadIdx.x;
  float4 f = *(const float4*)(X + (size_t)t*DM + tid*4);
  float4 b = *(const float4*)(X + (size_t)L*DM + (size_t)(L-1-t)*DM + tid*4);
  *(float4*)(MG + (size_t)t*2*DM + tid*4) = f;
  *(float4*)(MG + (size_t)t*2*DM + DM + tid*4) = b;
}

// ------------- merged -> split bf16 hi/lo (MFMA path) ----------------------
__global__ __launch_bounds__(128) void k_merge_bf(const float* __restrict__ X,
    ushort* __restrict__ hi, ushort* __restrict__ lo){
  int t = blockIdx.x, tid = threadIdx.x;
  float4 f = *(const float4*)(X + (size_t)t*DM + tid*4);
  float4 b = *(const float4*)(X + (size_t)L*DM + (size_t)(L-1-t)*DM + tid*4);
  ushort4 h4,l4;
  split2(f.x,h4.x,l4.x); split2(f.y,h4.y,l4.y); split2(f.z,h4.z,l4.z); split2(f.w,h4.w,l4.w);
  *(ushort4*)(hi + (size_t)t*2*DM + tid*4) = h4;
  *(ushort4*)(lo + (size_t)t*2*DM + tid*4) = l4;
  split2(b.x,h4.x,l4.x); split2(b.y,h4.y,l4.y); split2(b.z,h4.z,l4.z); split2(b.w,h4.w,l4.w);
  *(ushort4*)(hi + (size_t)t*2*DM + DM + tid*4) = h4;
  *(ushort4*)(lo + (size_t)t*2*DM + DM + tid*4) = l4;
}

extern "C" void kernel_launch(void* const* d_in, const int* in_sizes, int n_in,
                              void* d_out, int out_size, void* d_ws, size_t ws_size,
                              hipStream_t stream) {
  (void)in_sizes; (void)n_in; (void)out_size;
  const int*   tokens  = (const int*)d_in[0];
  const float* embedW  = (const float*)d_in[1];
  const float* f_in_proj = (const float*)d_in[2];
  const float* f_conv_w  = (const float*)d_in[3];
  const float* f_conv_b  = (const float*)d_in[4];
  const float* f_dt_bias = (const float*)d_in[5];
  const float* f_A_log   = (const float*)d_in[6];
  const float* f_D       = (const float*)d_in[7];
  const float* f_norm_w  = (const float*)d_in[8];
  const float* f_out_proj= (const float*)d_in[9];
  const float* f_ln_w    = (const float*)d_in[10];
  const float* f_ln_b    = (const float*)d_in[11];
  const float* b_in_proj = (const float*)d_in[12];
  const float* b_conv_w  = (const float*)d_in[13];
  const float* b_conv_b  = (const float*)d_in[14];
  const float* b_dt_bias = (const float*)d_in[15];
  const float* b_A_log   = (const float*)d_in[16];
  const float* b_D       = (const float*)d_in[17];
  const float* b_norm_w  = (const float*)d_in[18];
  const float* b_out_proj= (const float*)d_in[19];
  const float* b_ln_w    = (const float*)d_in[20];
  const float* b_ln_b    = (const float*)d_in[21];
  const float* mergeW    = (const float*)d_in[22];
  const float* fin_w     = (const float*)d_in[23];
  const float* fin_b     = (const float*)d_in[24];

  char* P = (char*)d_ws;
  float* X  = (float*)P; P += (size_t)2*L*DM*4;
  float* XN = (float*)P; P += (size_t)2*L*DM*4;
  float* ZX = (float*)P; P += (size_t)2*L*DPROJ*4;
  float* XC = (float*)P; P += (size_t)2*L*CDIM*4;
  float* DTb= (float*)P; P += (size_t)2*L*NH*4;
  float* LAb= (float*)P; P += (size_t)2*NH*NC*CQ*4;
  float* Yb = (float*)P; P += (size_t)2*L*DIN*4;
  float* ZB = (float*)P; P += (size_t)2*NH*NC*HD*DST*4;
  float* SB = (float*)P; P += (size_t)2*NH*NC*HD*DST*4;
  float* XG = (float*)P; P += (size_t)2*L*DIN*4;
  float* MG = (float*)P; P += (size_t)L*2*DM*4;
  float* FN = (float*)P; P += (size_t)L*DM*4;
  ushort* XNh = (ushort*)P; P += (size_t)2*L*DM*2;
  ushort* XNl = (ushort*)P; P += (size_t)2*L*DM*2;
  ushort* XGh = (ushort*)P; P += (size_t)2*L*DIN*2;
  ushort* XGl = (ushort*)P; P += (size_t)2*L*DIN*2;
  ushort* MGh = (ushort*)P; P += (size_t)L*2*DM*2;
  ushort* MGl = (ushort*)P; P += (size_t)L*2*DM*2;
  ushort* FNh = (ushort*)P; P += (size_t)L*DM*2;
  ushort* FNl = (ushort*)P; P += (size_t)L*DM*2;
  ushort* WipH = (ushort*)P; P += (size_t)2*4*IPS*2;
  ushort* WipL = (ushort*)P; P += (size_t)2*4*IPS*2;
  ushort* WopH = (ushort*)P; P += (size_t)2*4*OPS*2;
  ushort* WopL = (ushort*)P; P += (size_t)2*4*OPS*2;
  ushort* WmgH = (ushort*)P; P += (size_t)DM*2*DM*2;
  ushort* WmgL = (ushort*)P; P += (size_t)DM*2*DM*2;
  ushort* WemH = (ushort*)P; P += (size_t)32000*DM*2;
  ushort* WemL = (ushort*)P; P += (size_t)32000*DM*2;
  size_t need = (size_t)(P - (char*)d_ws);
  bool mf = (ws_size >= need);

  k_embed<<<L,128,0,stream>>>(tokens, embedW, X);

  if (mf){
    k_split_ip<<<2304,256,0,stream>>>(f_in_proj, WipH, WipL);
    k_split_ip<<<2304,256,0,stream>>>(b_in_proj, WipH+(size_t)4*IPS, WipL+(size_t)4*IPS);
    k_split_flat<<<1024,256,0,stream>>>(f_out_proj, WopH, WopL, 262144);
    k_split_flat<<<1024,256,0,stream>>>(b_out_proj, WopH+(size_t)4*OPS, WopL+(size_t)4*OPS, 262144);
    k_split_flat<<<256,256,0,stream>>>(mergeW, WmgH, WmgL, 65536);
    k_split_flat<<<8000,256,0,stream>>>(embedW, WemH, WemL, 2048000);

    for (int i=0;i<4;i++){
      k_ln_bf<<<2*L,128,0,stream>>>(X, XNh, XNl, f_ln_w+i*DM, f_ln_b+i*DM, b_ln_w+i*DM, b_ln_b+i*DM, L);
      k_gemm_mf<128,128,0><<<dim3(18,16),256,0,stream>>>(
          XNh, XNl, WipH+(size_t)i*IPS, WipL+(size_t)i*IPS,
          WipH+(size_t)(4+i)*IPS, WipL+(size_t)(4+i)*IPS, 1024, ZX, DPROJ, DM);
      k_convdt<<<2*L+128,256,0,stream>>>(ZX,
          f_conv_w+(size_t)i*CDIM*4, f_conv_b+(size_t)i*CDIM,
          b_conv_w+(size_t)i*CDIM*4, b_conv_b+(size_t)i*CDIM, XC,
          f_dt_bias+i*NH, f_A_log+i*NH, b_dt_bias+i*NH, b_A_log+i*NH, DTb, LAb);
      k_scanA<<<dim3(NC,NH,2),256,0,stream>>>(XC, DTb, LAb, Yb, ZB);
      k_scanB<<<dim3(NH,2,4),256,0,stream>>>(ZB, LAb, SB);
      k_scanC<<<dim3(NC,NH,2),256,0,stream>>>(XC, SB, LAb, f_D+i*NH, b_D+i*NH, Yb);
      k_rms_bf<<<2*L,256,0,stream>>>(Yb, ZX, f_norm_w+i*DIN, b_norm_w+i*DIN, XGh, XGl);
      k_gemm_mf<64,64,1><<<dim3(8,32),256,0,stream>>>(
          XGh, XGl, WopH+(size_t)i*OPS, WopL+(size_t)i*OPS,
          WopH+(size_t)(4+i)*OPS, WopL+(size_t)(4+i)*OPS, 1024, X, DM, DIN);
    }
    k_merge_bf<<<L,128,0,stream>>>(X, MGh, MGl);
    k_gemm_mf<64,64,0><<<dim3(8,16),256,0,stream>>>(
        MGh, MGl, WmgH, WmgL, WmgH, WmgL, 1<<30, XN, DM, 2*DM);
    k_ln_bf<<<L,128,0,stream>>>(XN, FNh, FNl, fin_w, fin_b, fin_w, fin_b, L);
    k_gemm_mf<128,128,0><<<dim3(250,8),256,0,stream>>>(
        FNh, FNl, WemH, WemL, WemH, WemL, 1<<30, (float*)d_out, 32000, DM);
  } else {
    for (int i=0;i<4;i++){
      k_ln<<<2*L,128,0,stream>>>(X, XN, f_ln_w+i*DM, f_ln_b+i*DM, b_ln_w+i*DM, b_ln_b+i*DM, L);
      k_gemm<0><<<dim3((DPROJ+63)/64, (2*L)/64),256,0,stream>>>(
          XN, f_in_proj+(size_t)i*DPROJ*DM, b_in_proj+(size_t)i*DPROJ*DM, L,
          ZX, 2*L, DPROJ, DM);
      k_convdt<<<2*L+128,256,0,stream>>>(ZX,
          f_conv_w+(size_t)i*CDIM*4, f_conv_b+(size_t)i*CDIM,
          b_conv_w+(size_t)i*CDIM*4, b_conv_b+(size_t)i*CDIM, XC,
          f_dt_bias+i*NH, f_A_log+i*NH, b_dt_bias+i*NH, b_A_log+i*NH, DTb, LAb);
      k_scanA<<<dim3(NC,NH,2),256,0,stream>>>(XC, DTb, LAb, Yb, ZB);
      k_scanB<<<dim3(NH,2,4),256,0,stream>>>(ZB, LAb, SB);
      k_scanC<<<dim3(NC,NH,2),256,0,stream>>>(XC, SB, LAb, f_D+i*NH, b_D+i*NH, Yb);
      k_rms<<<2*L,256,0,stream>>>(Yb, ZX, f_norm_w+i*DIN, b_norm_w+i*DIN, XG);
      k_gemm<1><<<dim3(DM/64, (2*L)/64),256,0,stream>>>(
          XG, f_out_proj+(size_t)i*DM*DIN, b_out_proj+(size_t)i*DM*DIN, L,
          X, 2*L, DM, DIN);
    }
    k_merge<<<L,128,0,stream>>>(X, MG);
    k_gemm<0><<<dim3(DM/64, L/64),256,0,stream>>>(MG, mergeW, mergeW, 1<<30, XN, L, DM, 2*DM);
    k_ln<<<L,128,0,stream>>>(XN, FN, fin_w, fin_b, fin_w, fin_b, L);
    k_gemm<0><<<dim3(32000/64, L/64),256,0,stream>>>(FN, embedW, embedW, 1<<30,
        (float*)d_out, L, 32000, DM);
  }
}